// Round 9
// baseline (3153.704 us; speedup 1.0000x reference)
//
#include <hip/hip_runtime.h>
#include <hip/hip_bf16.h>
#include <math.h>

#define B_ 16
#define T_ 512
#define C_ 1024
#define H_ 16
#define D_ 64
#define F_ 4096
#define L_ 8
#define M_ (B_*T_)   // 8192 rows

typedef __hip_bfloat16 bf16;
typedef __attribute__((ext_vector_type(8))) short short8;
typedef __attribute__((ext_vector_type(4))) float f32x4;
typedef __attribute__((ext_vector_type(16))) float f32x16;

__device__ __forceinline__ short f2bs(float x){
  union { __hip_bfloat16 h; short s; } u;
  u.h = __float2bfloat16(x);
  return u.s;
}
__device__ __forceinline__ float bs2f(unsigned short s){
  union { float f; unsigned u; } v; v.u = ((unsigned)s) << 16; return v.f;
}

__device__ __forceinline__ void gload16(const void* g, void* l){
  __builtin_amdgcn_global_load_lds((const __attribute__((address_space(1))) void*)g,
      (__attribute__((address_space(3))) void*)l, 16, 0, 0);
}

// ---------------- weight transpose+convert: W[K,N] f32 -> Wt[N,K] bf16 ----------------
__global__ __launch_bounds__(256) void convert_w(
    const float* __restrict__ Wq, const float* __restrict__ Wk,
    const float* __restrict__ Wv, const float* __restrict__ Wo,
    const float* __restrict__ W1, const float* __restrict__ W2,
    bf16* __restrict__ slab)
{
  __shared__ float t[32][33];
  int bid = blockIdx.x;
  const float* src; bf16* dst; int K, N, tile;
  if (bid < 4096) {
    int m = bid >> 10;
    src = (m==0)?Wq:(m==1)?Wk:(m==2)?Wv:Wo;
    dst = slab + (size_t)m*C_*C_;
    K = C_; N = C_; tile = bid & 1023;
  } else if (bid < 8192) {
    src = W1; dst = slab + (size_t)4*C_*C_; K = C_; N = F_; tile = bid - 4096;
  } else {
    src = W2; dst = slab + (size_t)4*C_*C_ + (size_t)C_*F_; K = F_; N = C_; tile = bid - 8192;
  }
  int tilesN = N >> 5;
  int tk = tile / tilesN, tn = tile % tilesN;
  int r = threadIdx.x >> 5, c = threadIdx.x & 31;
  #pragma unroll
  for (int i=0;i<4;i++)
    t[r + i*8][c] = src[(size_t)(tk*32 + r + i*8)*N + tn*32 + c];
  __syncthreads();
  #pragma unroll
  for (int i=0;i<4;i++)
    dst[(size_t)(tn*32 + r + i*8)*K + tk*32 + c] = __float2bfloat16(t[c][r + i*8]);
}

// ---------------- LayerNorm (+optional bf16 split-K partial reduction) ----------------
__global__ __launch_bounds__(256) void ln_k(float* __restrict__ h,
    const bf16* __restrict__ p0, const bf16* __restrict__ p1, int hasP,
    const float* __restrict__ g, const float* __restrict__ be, bf16* __restrict__ out)
{
  int row = blockIdx.x;
  int tid = threadIdx.x;
  int w = tid >> 6, lane = tid & 63;
  size_t base = (size_t)row*C_;
  float4 v = reinterpret_cast<const float4*>(h + base)[tid];
  if (hasP){
    ushort4 a = reinterpret_cast<const ushort4*>(p0 + base)[tid];
    ushort4 b = reinterpret_cast<const ushort4*>(p1 + base)[tid];
    v.x += bs2f(a.x) + bs2f(b.x); v.y += bs2f(a.y) + bs2f(b.y);
    v.z += bs2f(a.z) + bs2f(b.z); v.w += bs2f(a.w) + bs2f(b.w);
    reinterpret_cast<float4*>(h + base)[tid] = v;
  }
  float s = v.x+v.y+v.z+v.w;
  float ss = v.x*v.x+v.y*v.y+v.z*v.z+v.w*v.w;
  #pragma unroll
  for (int o=32;o>=1;o>>=1){ s += __shfl_xor(s,o); ss += __shfl_xor(ss,o); }
  __shared__ float sa[4], sb[4];
  if (lane==0){ sa[w]=s; sb[w]=ss; }
  __syncthreads();
  s  = sa[0]+sa[1]+sa[2]+sa[3];
  ss = sb[0]+sb[1]+sb[2]+sb[3];
  float mean = s * (1.0f/C_);
  float var  = ss * (1.0f/C_) - mean*mean;
  float rs = rsqrtf(var + 1e-5f);
  float4 gv = reinterpret_cast<const float4*>(g)[tid];
  float4 bv = reinterpret_cast<const float4*>(be)[tid];
  ushort4 o;
  o.x = (unsigned short)f2bs((v.x-mean)*rs*gv.x + bv.x);
  o.y = (unsigned short)f2bs((v.y-mean)*rs*gv.y + bv.y);
  o.z = (unsigned short)f2bs((v.z-mean)*rs*gv.z + bv.z);
  o.w = (unsigned short)f2bs((v.w-mean)*rs*gv.w + bv.w);
  reinterpret_cast<ushort4*>(out + base)[tid] = o;
}

// ---------------- 256x256 GEMM, 32x32x16 MFMA, pipelined 2-fat-phase/K-tile ----------------
// phA: reads g0 (A-h0 frags + B-all, ks-grouped); STG pair1; WV8; BAR1;
//      reads g1 (A-h1); sched_barrier; 16 MFMA (g0); BAR2.
// phB: STG pair2; 16 MFMA (g1); WV6; BAR3.
// Ring identical to verified r7 ledger (WV8 moved pre-BAR1; counts unchanged):
//  even: pair1=[Bo1,Ao1]<-u+1, pair2=[Be0,Ae0]<-u+2; odd: pair1=[Be1,Ae1]<-u+2, pair2=[Bo0,Ao0]<-u+3.
//  Steady state entering phA = 6 outstanding [Ae1,Bo0,Ao0]; WV8 retires current A-h1 slot
//  before its g1 reads; WV6 retires next phA's g0 set. All overwrites >=1 barrier after read-drain.
// EPI: 0 = bf16+bias, 1 = exact-GELU bf16+bias, 2 = bf16 partial store (+bias when kz==0)
template<int EPI, int QKV3>
__global__ __launch_bounds__(512,1) void gemm8_k(
    const bf16* __restrict__ A, int lda,
    const bf16* __restrict__ Bt, int ldb,
    const float* __restrict__ b0, const float* __restrict__ b1v,
    const float* __restrict__ b2v, int addbias,
    void* __restrict__ outp, int N, int Ksub)
{
  __shared__ char lds[131072];
  // slot byte offsets: Ae=0, Be=32768, Ao=65536, Bo=98304; halves at +0/+16384

  const int tid = threadIdx.x, lane = tid & 63;
  const int w = tid >> 6, wr = w >> 2, wc = w & 3;
  const int l31 = lane & 31, hi5 = lane >> 5, l7 = lane & 7;

  // bijective XCD swizzle (all grids here have nwg % 8 == 0)
  int bid = blockIdx.y * gridDim.x + blockIdx.x;
  int cpx = (gridDim.x * gridDim.y) >> 3;
  int swz = (bid & 7) * cpx + (bid >> 3);
  int tn = swz % gridDim.x, tm = swz / gridDim.x;
  const int R0 = tm * 256, C0 = tn * 256;
  const int kz = blockIdx.z;
  const bf16* Ab = A  + (size_t)kz * Ksub;
  const bf16* Bb = Bt + (size_t)kz * Ksub;
  const int KT = Ksub >> 6;   // even, >= 4

  // staging: scalar row-bases + per-lane 32-bit offset (source-side XOR swizzle)
  const int rS = tid >> 3;
  const int cS = (tid & 7) ^ (rS & 7);
  const int offLa = rS * lda + cS * 8;
  const int offLb = rS * ldb + cS * 8;
  const int ld64a = lda << 6, ld64b = ldb << 6;
  const bf16* pA0 = Ab + (size_t)R0 * lda;
  const bf16* pA1 = pA0 + ((size_t)lda << 7);
  const bf16* pB0 = Bb + (size_t)C0 * ldb;
  const bf16* pB1 = pB0 + ((size_t)ldb << 7);

#define STG(slotOff, pb, ld64, offv, tile) { \
    int ut_ = (tile) < KT ? (tile) : KT-1; \
    const bf16* q_ = (pb) + (size_t)(ut_ << 6); \
    gload16(q_ + (offv), &lds[(slotOff) + tid*16]); \
    gload16(q_ + (offv) + (ld64), &lds[(slotOff) + 8192 + tid*16]); }

  // ds-read addressing: row<<7 + ((ks*2+hi5)^(row&7))<<4 ; row&7 == lane&7 for all frags
  int sl[4];
  #pragma unroll
  for (int ks=0;ks<4;ks++) sl[ks] = (((ks*2 + hi5) ^ l7) << 4);
  int aB[2], aBO[2];
  #pragma unroll
  for (int p=0;p<2;p++){ aB[p] = ((wr*64 + p*32 + l31) << 7); aBO[p] = aB[p] + 65536; }
  const int bB  = ((wc*32 + l31) << 7) + 32768;
  const int bBO = bB + 65536;

  // prologue: tile0 [Be0,Ae0,Be1,Ae1], tile1 [Bo0,Ao0]; WV6 retires {Be0,Ae0,Be1} = g0 set
  STG(32768,       pB0, ld64b, offLb, 0)
  STG(0,           pA0, ld64a, offLa, 0)
  STG(32768+16384, pB1, ld64b, offLb, 0)
  STG(16384,       pA1, ld64a, offLa, 0)
  STG(98304,       pB0, ld64b, offLb, 1)
  STG(65536,       pA0, ld64a, offLa, 1)
  asm volatile("s_waitcnt vmcnt(6)" ::: "memory");
  asm volatile("s_barrier" ::: "memory");

  f32x16 acc[4][2];
  #pragma unroll
  for (int mt=0;mt<4;mt++)
    #pragma unroll
    for (int nt=0;nt<2;nt++)
      #pragma unroll
      for (int r=0;r<16;r++) acc[mt][nt][r] = 0.f;

  short8 a0[2][4], a1[2][4], bfv2[2][4];

#define RDG0(AEB, BEB) { \
    _Pragma("unroll") \
    for (int ks=0;ks<4;ks++){ \
      bfv2[0][ks] = *reinterpret_cast<const short8*>(&lds[(BEB) + sl[ks]]); \
      bfv2[1][ks] = *reinterpret_cast<const short8*>(&lds[(BEB) + sl[ks] + 16384]); \
      a0[0][ks]   = *reinterpret_cast<const short8*>(&lds[(AEB)[0] + sl[ks]]); \
      a0[1][ks]   = *reinterpret_cast<const short8*>(&lds[(AEB)[1] + sl[ks]]); } }
#define RDG1(AEB) { \
    _Pragma("unroll") \
    for (int ks=0;ks<4;ks++){ \
      a1[0][ks] = *reinterpret_cast<const short8*>(&lds[(AEB)[0] + sl[ks] + 16384]); \
      a1[1][ks] = *reinterpret_cast<const short8*>(&lds[(AEB)[1] + sl[ks] + 16384]); } }
#define MMG(AF, mb) { \
    __builtin_amdgcn_s_setprio(1); \
    _Pragma("unroll") \
    for (int ks=0;ks<4;ks++){ \
      _Pragma("unroll") \
      for (int p=0;p<2;p++){ \
        _Pragma("unroll") \
        for (int nt=0;nt<2;nt++) \
          acc[(mb)+p][nt] = __builtin_amdgcn_mfma_f32_32x32x16_bf16( \
              AF[p][ks], bfv2[nt][ks], acc[(mb)+p][nt], 0,0,0); } } \
    __builtin_amdgcn_s_setprio(0); }
#define BAR asm volatile("s_barrier" ::: "memory")
#define WV8 asm volatile("s_waitcnt vmcnt(8)" ::: "memory")
#define WV6 asm volatile("s_waitcnt vmcnt(6)" ::: "memory")

  for (int it=0; it<KT/2; ++it){
    int u = 2*it;
    // ---- phA even (tile u) ----
    RDG0(aB, bB)
    STG(98304+16384, pB1, ld64b, offLb, u+1)   // Bo1 <- u+1
    STG(65536+16384, pA1, ld64a, offLa, u+1)   // Ao1 <- u+1
    WV8; BAR;                                  // retires Ae1(u); all waves synced
    RDG1(aB)
    __builtin_amdgcn_sched_barrier(0);
    MMG(a0, 0)
    BAR;
    // ---- phB even ----
    STG(32768, pB0, ld64b, offLb, u+2)         // Be0 <- u+2
    STG(0,     pA0, ld64a, offLa, u+2)         // Ae0 <- u+2
    MMG(a1, 2)
    WV6; BAR;                                  // retires Bo0,Ao0,Bo1 (next phA g0 set)
    // ---- phA odd (tile u+1) ----
    RDG0(aBO, bBO)
    STG(32768+16384, pB1, ld64b, offLb, u+2)   // Be1 <- u+2
    STG(16384,       pA1, ld64a, offLa, u+2)   // Ae1 <- u+2
    WV8; BAR;                                  // retires Ao1(u+1)
    RDG1(aBO)
    __builtin_amdgcn_sched_barrier(0);
    MMG(a0, 0)
    BAR;
    // ---- phB odd ----
    STG(98304, pB0, ld64b, offLb, u+3)         // Bo0 <- u+3
    STG(65536, pA0, ld64a, offLa, u+3)         // Ao0 <- u+3
    MMG(a1, 2)
    WV6; BAR;                                  // retires Be0,Ae0,Be1
  }
  asm volatile("s_waitcnt vmcnt(0)" ::: "memory");
#undef RDG0
#undef RDG1
#undef MMG
#undef BAR
#undef WV8
#undef WV6
#undef STG

  // epilogue: C/D layout col=lane&31, row=(r&3)+8*(r>>2)+4*(lane>>5)  [m74/m101]
  int sel = C0 >> 10;
  const float* bp = QKV3 ? (sel==0 ? b0 : (sel==1 ? b1v : b2v)) : b0;
  int cb0 = QKV3 ? (C0 & 1023) : C0;
  int ab = addbias && (kz == 0);
  #pragma unroll
  for (int mt=0; mt<4; mt++){
    int rowb = R0 + (mt>>1)*128 + wr*64 + (mt&1)*32 + 4*hi5;
    #pragma unroll
    for (int nt=0; nt<2; nt++){
      int colrel = nt*128 + wc*32 + l31;
      int col = C0 + colrel;
      float bb = ab ? bp[cb0 + colrel] : 0.f;
      #pragma unroll
      for (int r=0;r<16;r++){
        int row = rowb + (r&3) + 8*(r>>2);
        float vv = acc[mt][nt][r] + bb;
        if (EPI==0){
          ((bf16*)outp)[(size_t)row*N + col] = __float2bfloat16(vv);
        } else if (EPI==1){
          float gl = 0.5f*vv*(1.0f + erff(vv*0.70710678118654752f));
          ((bf16*)outp)[(size_t)row*N + col] = __float2bfloat16(gl);
        } else {
          ((bf16*)outp)[(size_t)kz*M_*N + (size_t)row*N + col] = __float2bfloat16(vv);
        }
      }
    }
  }
}

// ---------------- Flash attention: K direct from global (L2-hit), V staged in LDS ----------------
__global__ __launch_bounds__(512,4) void attn_k(const bf16* __restrict__ qkv,
    bf16* __restrict__ y)
{
  __shared__ bf16 Vs[T_*64];   // 64 KB, shifted-slot rows
  const int SQ = 3*C_;
  int tid = threadIdx.x, lane = tid&63, w = tid>>6;
  int b = blockIdx.z, h = blockIdx.y, qt = blockIdx.x;
  size_t baseQ = ((size_t)b*T_)*SQ + (size_t)h*64;
  size_t baseK = baseQ + 1024;
  size_t baseV = baseQ + 2048;
  size_t baseY = ((size_t)b*T_)*C_ + (size_t)h*64;

  #pragma unroll
  for (int i=0;i<8;i++){
    int cc = i*512 + tid;
    int row = cc>>3, ch = cc&7;
    short8 vv = *reinterpret_cast<const short8*>(qkv + baseV + (size_t)row*SQ + ch*8);
    int slotV = (ch + 2*((row>>3)&3)) & 7;
    *reinterpret_cast<short8*>((char*)Vs + row*128 + slotV*16) = vv;
  }
  __syncthreads();

  int g = lane>>4, r16 = lane&15;
  int qrow0 = qt*256 + w*32;
  short8 qf[2][2];
  #pragma unroll
  for (int s=0;s<2;s++)
    #pragma unroll
    for (int c=0;c<2;c++)
      qf[s][c] = *reinterpret_cast<const short8*>(qkv + baseQ + (size_t)(qrow0 + s*16 + r16)*SQ + c*32 + g*8);

  const f32x4 fz = {0.f,0.f,0.f,0.f};
  float mreg[2] = {-1e30f, -1e30f};
  float lsum[2] = {0.f, 0.f};
  f32x4 yacc[2][4];
  #pragma unroll
  for (int s=0;s<2;s++)
    #pragma unroll
    for (int dt=0;dt<4;dt++) yacc[s][dt] = fz;

  const float SC = 0.18033688011112043f; // (1/sqrt(64)) * log2(e)
  int rl0 = ((r16>>2)<<3) + (r16&3);     // k-row permutation so PV B-frag is lane-local
  const bf16* kb = qkv + baseK;

  for (int kt=0; kt<16; ++kt){
    int rowA = kt*32 + rl0;
    int rowB = rowA + 4;
    short8 kf0[2], kf1[2];
    #pragma unroll
    for (int c=0;c<2;c++){
      kf0[c] = *reinterpret_cast<const short8*>(kb + (size_t)rowA*SQ + c*32 + g*8);
      kf1[c] = *reinterpret_cast<const short8*>(kb + (size_t)rowB*SQ + c*32 + g*8);
    }
    short8 pf[2];
    #pragma unroll
    for (int s=0;s<2;s++){
      f32x4 st0 = fz, st1 = fz;
      st0 = __builtin_amdgcn_mfma_f32_16x16x32_bf16(kf0[0], qf[s][0], st0, 0,0,0);
      st0 = __builtin_amdgcn_mfma_f32_16x16x32_bf16(kf0[1], qf[s][1], st0, 0,0,0);
      st1 = __builtin_amdgcn_mfma_f32_16x16x32_bf16(kf1[0], qf[s][0], st1, 0,0,0);
      st1 = __builtin_amdgcn_mfma_f32_16x16x32_bf16(kf1[1], qf[s][1], st1, 0,0,0);
      float p0[4], p1[4];
      float tm = -1e30f;
      #pragma unroll
      for (int r=0;r<4;r++){
        p0[r] = st0[r]*SC; p1[r] = st1[r]*SC;
        tm = fmaxf(tm, fmaxf(p0[r], p1[r]));
      }
      tm = fmaxf(tm, __shfl_xor(tm, 16));
      tm = fmaxf(tm, __shfl_xor(tm, 32));
      float nm = fmaxf(mreg[s], tm);
      float f = exp2f(mreg[s] - nm);
      mreg[s] = nm;
      float psum = 0.f;
      #pragma unroll
      for (int r=0;r<4;r++){
        p0[r] = exp2f(p0[r]-nm); p1[r] = exp2f(p1[r]-nm);
        psum += p0[r] + p1[r];
      }
      lsum[s] = lsum[s]*f + psum;
      #pragma unroll
      for (int dt=0;dt<4;dt++) yacc[s][dt] *= f;
      short8 pp;
      pp[0]=f2bs(p0[0]); pp[1]=f2bs(p0[1]); pp[2]=f2bs(p0[2]); pp[3]=f2bs(p0[3]);
      pp[4]=f2bs(p1[0]); pp[5]=f2bs(p1[1]); pp[6]=f2bs(p1[2]); pp[7]=f2bs(p1[3]);
      pf[s] = pp;
    }
    #pragma unroll
    for (int dt=0;dt<4;dt++){
      short8 vfdt;
      #pragma unroll
      for (int j=0;j<8;j++){
        int row = kt*32 + g*8 + j;
        int col = dt*16 + r16;
        int slot = ((col>>3) + 2*((row>>3)&3)) & 7;
        vfdt[j] = *reinterpret_cast<const short*>((char*)Vs + row*128 + slot*16 + (col&7)*2);
      }
      yacc[0][dt] = __builtin_amdgcn_mfma_f32_16x16x32_bf16(vfdt, pf[0], yacc[0][dt], 0,0,0);
      yacc[1][dt] = __builtin_amdgcn_mfma_f32_16x16x32_bf16(vfdt, pf[1], yacc[1][dt], 0,0,0);
    }
  }

  #pragma unroll
  for (int s=0;s<2;s++){
    float ls = lsum[s];
    ls += __shfl_xor(ls, 16);
    ls += __shfl_xor(ls, 32);
    float inv = 1.0f/ls;
    int qrow = qrow0 + s*16 + r16;
    #pragma unroll
    for (int dt=0;dt<4;dt++){
      ushort4 o;
      o.x = (unsigned short)f2bs(yacc[s][dt][0]*inv);
      o.y = (unsigned short)f2bs(yacc[s][dt][1]*inv);
      o.z = (unsigned short)f2bs(yacc[s][dt][2]*inv);
      o.w = (unsigned short)f2bs(yacc[s][dt][3]*inv);
      *reinterpret_cast<ushort4*>(y + baseY + (size_t)qrow*C_ + dt*16 + g*4) = o;
    }
  }
}

// ---------------- final LN (last token only, + W2 bf16 partials) + pooling head ----------------
__global__ __launch_bounds__(256) void head_k(const float* __restrict__ hbuf,
    const bf16* __restrict__ p0, const bf16* __restrict__ p1,
    const float* __restrict__ gf, const float* __restrict__ bfv,
    const float* __restrict__ Wp, const float* __restrict__ bp, float* __restrict__ out)
{
  int b = blockIdx.x, kc = blockIdx.y, tid = threadIdx.x;
  int w = tid >> 6, lane = tid & 63;
  size_t base = ((size_t)(b*T_ + T_-1))*C_;
  float4 v = reinterpret_cast<const float4*>(hbuf + base)[tid];
  ushort4 a = reinterpret_cast<const ushort4*>(p0 + base)[tid];
  ushort4 c = reinterpret_cast<const ushort4*>(p1 + base)[tid];
  v.x += bs2f(a.x) + bs2f(c.x); v.y += bs2f(a.y) + bs2f(c.y);
  v.z += bs2f(a.z) + bs2f(c.z); v.w += bs2f(a.w) + bs2f(c.w);
  float s = v.x+v.y+v.z+v.w;
  float ss = v.x*v.x+v.y*v.y+v.z*v.z+v.w*v.w;
  #pragma unroll
  for (int o=32;o>=1;o>>=1){ s += __shfl_xor(s,o); ss += __shfl_xor(ss,o); }
  __shared__ float sa[4], sb[4];
  if (lane==0){ sa[w]=s; sb[w]=ss; }
  __syncthreads();
  s  = sa[0]+sa[1]+sa[2]+sa[3];
  ss = sb[0]+sb[1]+sb[2]+sb[3];
  float mean = s * (1.0f/C_);
  float var  = ss * (1.0f/C_) - mean*mean;
  float rs = rsqrtf(var + 1e-5f);
  __shared__ float nrm[C_];
  float4 gv = reinterpret_cast<const float4*>(gf)[tid];
  float4 bv = reinterpret_cast<const float4*>(bfv)[tid];
  nrm[tid*4+0] = (v.x-mean)*rs*gv.x + bv.x;
  nrm[tid*4+1] = (v.y-mean)*rs*gv.y + bv.y;
  nrm[tid*4+2] = (v.z-mean)*rs*gv.z + bv.z;
  nrm[tid*4+3] = (v.w-mean)*rs*gv.w + bv.w;
  __syncthreads();
  float acc = (kc==0) ? bp[tid] : 0.f;
  int k0 = kc*64;
  #pragma unroll 8
  for (int kk=k0; kk<k0+64; kk++) acc += nrm[kk]*Wp[(size_t)kk*256 + tid];
  atomicAdd(&out[b*256 + tid], acc);
}

extern "C" void kernel_launch(void* const* d_in, const int* in_sizes, int n_in,
                              void* d_out, int out_size, void* d_ws, size_t ws_size,
                              hipStream_t stream)
{
  const float* x  = (const float*)d_in[0];
  const float* Wq = (const float*)d_in[1];
  const float* bq = (const float*)d_in[2];
  const float* Wk = (const float*)d_in[3];
  const float* bk = (const float*)d_in[4];
  const float* Wv = (const float*)d_in[5];
  const float* bv = (const float*)d_in[6];
  const float* Wo = (const float*)d_in[7];
  const float* bo = (const float*)d_in[8];
  const float* g1 = (const float*)d_in[9];
  const float* be1= (const float*)d_in[10];
  const float* g2 = (const float*)d_in[11];
  const float* be2= (const float*)d_in[12];
  const float* W1 = (const float*)d_in[13];
  const float* b1 = (const float*)d_in[14];
  const float* W2 = (const float*)d_in[15];
  const float* b2 = (const float*)d_in[16];
  const float* gf = (const float*)d_in[17];
  const float* bfv= (const float*)d_in[18];
  const float* Wp = (const float*)d_in[19];
  const float* bp = (const float*)d_in[20];
  float* out = (float*)d_out;

  const size_t NEED = 209715200;
  if (ws_size < NEED) return;

  char* ws = (char*)d_ws;
  float* hbuf = (float*)ws;                      //   0 .. 32MiB  fp32 residual
  bf16* abuf  = (bf16*)(ws + 33554432);          //  32 .. 48MiB
  bf16* qkv   = (bf16*)(ws + 50331648);          //  48 .. 96MiB   [M,3C] (aliased by mid)
  bf16* ybuf  = (bf16*)(ws + 100663296);         //  96 ..112MiB   (aliased by mid)
  bf16* mid   = (bf16*)(ws + 50331648);          //  48 ..112MiB   [M,F]
  bf16* slab  = (bf16*)(ws + 117440512);         // 112 ..136MiB   per-layer bf16 Wt
  bf16* part  = (bf16*)(ws + 142606336);         // 136 ..168MiB   2x [M,C] bf16 split-K partials

  hipMemcpyAsync(hbuf, x, (size_t)M_*C_*sizeof(float), hipMemcpyDeviceToDevice, stream);
  hipMemsetAsync(d_out, 0, (size_t)out_size*sizeof(float), stream);

  for (int l=0; l<L_; ++l){
    size_t oCC = (size_t)l*C_*C_, oC = (size_t)l*C_;
    size_t oCF = (size_t)l*C_*F_, oF = (size_t)l*F_;
    convert_w<<<12288, 256, 0, stream>>>(Wq+oCC, Wk+oCC, Wv+oCC, Wo+oCC, W1+oCF, W2+oCF, slab);
    // ln1: fold in previous layer's W2 partials (none at l==0)
    ln_k<<<M_, 256, 0, stream>>>(hbuf, part, part + (size_t)M_*C_, l>0 ? 1:0, g1+oC, be1+oC, abuf);
    // fused QKV: [8192,1024] @ [3072,1024]^T -> [8192,3072]
    gemm8_k<0,1><<<dim3(12,32), 512, 0, stream>>>(abuf, C_, slab, C_,
        bq+oC, bk+oC, bv+oC, 1, qkv, 3*C_, C_);
    attn_k<<<dim3(2, H_, B_), 512, 0, stream>>>(qkv, ybuf);
    // Wo: split-K=2 -> bf16 partials
    gemm8_k<2,0><<<dim3(4,32,2), 512, 0, stream>>>(ybuf, C_, slab + (size_t)3*C_*C_, C_,
        bo+oC, bo+oC, bo+oC, 1, part, C_, C_/2);
    // ln2: fold in Wo partials
    ln_k<<<M_, 256, 0, stream>>>(hbuf, part, part + (size_t)M_*C_, 1, g2+oC, be2+oC, abuf);
    // W1: [8192,1024] @ [4096,1024]^T -> GELU -> [8192,4096]
    gemm8_k<1,0><<<dim3(16,32), 512, 0, stream>>>(abuf, C_, slab + (size_t)4*C_*C_, C_,
        b1+oF, b1+oF, b1+oF, 1, mid, F_, C_);
    // W2: split-K=2 -> bf16 partials (folded by next ln1 / head)
    gemm8_k<2,0><<<dim3(4,32,2), 512, 0, stream>>>(mid, F_, slab + (size_t)4*C_*C_ + (size_t)C_*F_, F_,
        b2+oC, b2+oC, b2+oC, 1, part, C_, F_/2);
  }
  head_k<<<dim3(B_,16), 256, 0, stream>>>(hbuf, part, part + (size_t)M_*C_,
      gf, bfv, Wp, bp, out);
}

// Round 10
// 3153.105 us; speedup vs baseline: 1.0002x; 1.0002x over previous
//
#include <hip/hip_runtime.h>
#include <hip/hip_bf16.h>
#include <math.h>

#define B_ 16
#define T_ 512
#define C_ 1024
#define H_ 16
#define D_ 64
#define F_ 4096
#define L_ 8
#define M_ (B_*T_)   // 8192 rows

typedef __hip_bfloat16 bf16;
typedef __attribute__((ext_vector_type(8))) short short8;
typedef __attribute__((ext_vector_type(4))) float f32x4;

__device__ __forceinline__ short f2bs(float x){
  union { __hip_bfloat16 h; short s; } u;
  u.h = __float2bfloat16(x);
  return u.s;
}
__device__ __forceinline__ float bs2f(unsigned short s){
  union { float f; unsigned u; } v; v.u = ((unsigned)s) << 16; return v.f;
}

__device__ __forceinline__ void gload16(const void* g, void* l){
  __builtin_amdgcn_global_load_lds((const __attribute__((address_space(1))) void*)g,
      (__attribute__((address_space(3))) void*)l, 16, 0, 0);
}

// ---------------- weight transpose+convert: W[K,N] f32 -> Wt[N,K] bf16 ----------------
__global__ __launch_bounds__(256) void convert_w(
    const float* __restrict__ Wq, const float* __restrict__ Wk,
    const float* __restrict__ Wv, const float* __restrict__ Wo,
    const float* __restrict__ W1, const float* __restrict__ W2,
    bf16* __restrict__ slab)
{
  __shared__ float t[32][33];
  int bid = blockIdx.x;
  const float* src; bf16* dst; int K, N, tile;
  if (bid < 4096) {
    int m = bid >> 10;
    src = (m==0)?Wq:(m==1)?Wk:(m==2)?Wv:Wo;
    dst = slab + (size_t)m*C_*C_;
    K = C_; N = C_; tile = bid & 1023;
  } else if (bid < 8192) {
    src = W1; dst = slab + (size_t)4*C_*C_; K = C_; N = F_; tile = bid - 4096;
  } else {
    src = W2; dst = slab + (size_t)4*C_*C_ + (size_t)C_*F_; K = F_; N = C_; tile = bid - 8192;
  }
  int tilesN = N >> 5;
  int tk = tile / tilesN, tn = tile % tilesN;
  int r = threadIdx.x >> 5, c = threadIdx.x & 31;
  #pragma unroll
  for (int i=0;i<4;i++)
    t[r + i*8][c] = src[(size_t)(tk*32 + r + i*8)*N + tn*32 + c];
  __syncthreads();
  #pragma unroll
  for (int i=0;i<4;i++)
    dst[(size_t)(tn*32 + r + i*8)*K + tk*32 + c] = __float2bfloat16(t[c][r + i*8]);
}

// ---------------- LayerNorm (+optional bf16 split-K partial reduction) ----------------
__global__ __launch_bounds__(256) void ln_k(float* __restrict__ h,
    const bf16* __restrict__ p0, const bf16* __restrict__ p1, int hasP,
    const float* __restrict__ g, const float* __restrict__ be, bf16* __restrict__ out)
{
  int row = blockIdx.x;
  int tid = threadIdx.x;
  int w = tid >> 6, lane = tid & 63;
  size_t base = (size_t)row*C_;
  float4 v = reinterpret_cast<const float4*>(h + base)[tid];
  if (hasP){
    ushort4 a = reinterpret_cast<const ushort4*>(p0 + base)[tid];
    ushort4 b = reinterpret_cast<const ushort4*>(p1 + base)[tid];
    v.x += bs2f(a.x) + bs2f(b.x); v.y += bs2f(a.y) + bs2f(b.y);
    v.z += bs2f(a.z) + bs2f(b.z); v.w += bs2f(a.w) + bs2f(b.w);
    reinterpret_cast<float4*>(h + base)[tid] = v;
  }
  float s = v.x+v.y+v.z+v.w;
  float ss = v.x*v.x+v.y*v.y+v.z*v.z+v.w*v.w;
  #pragma unroll
  for (int o=32;o>=1;o>>=1){ s += __shfl_xor(s,o); ss += __shfl_xor(ss,o); }
  __shared__ float sa[4], sb[4];
  if (lane==0){ sa[w]=s; sb[w]=ss; }
  __syncthreads();
  s  = sa[0]+sa[1]+sa[2]+sa[3];
  ss = sb[0]+sb[1]+sb[2]+sb[3];
  float mean = s * (1.0f/C_);
  float var  = ss * (1.0f/C_) - mean*mean;
  float rs = rsqrtf(var + 1e-5f);
  float4 gv = reinterpret_cast<const float4*>(g)[tid];
  float4 bv = reinterpret_cast<const float4*>(be)[tid];
  ushort4 o;
  o.x = (unsigned short)f2bs((v.x-mean)*rs*gv.x + bv.x);
  o.y = (unsigned short)f2bs((v.y-mean)*rs*gv.y + bv.y);
  o.z = (unsigned short)f2bs((v.z-mean)*rs*gv.z + bv.z);
  o.w = (unsigned short)f2bs((v.w-mean)*rs*gv.w + bv.w);
  reinterpret_cast<ushort4*>(out + base)[tid] = o;
}

// ---------------- 128x128 GEMM, m97 structure + L2-blocked order + LDS XOR swizzle ----------------
// BK=32, 4 waves, 32KB LDS double-buffer -> ~5 resident blocks/CU (TLP hides barrier drain).
// Block order: XCD-bijective swizzle, then 8-wide bx-chunks x all by (B chunk stays L2-hot).
// LDS swizzle: stage src col ch^((row>>1)&3) into linear slot ch; read slot g^((r16>>1)&3).
// EPI: 0 = bf16+bias, 1 = exact-GELU bf16+bias, 2 = bf16 partial store (bias when kz==0)
template<int EPI, int QKV3>
__global__ __launch_bounds__(256) void gemm_k(
    const bf16* __restrict__ A, int lda,
    const bf16* __restrict__ Bt, int ldb,
    const float* __restrict__ b0, const float* __restrict__ b1v,
    const float* __restrict__ b2v,
    void* __restrict__ outp, int N, int Ksub)
{
  __shared__ bf16 As[2][128*32];
  __shared__ bf16 Bs[2][128*32];
  int tid = threadIdx.x, lane = tid&63, w = tid>>6;
  int wr = w>>1, wc = w&1;

  // XCD-bijective swizzle, then (8-wide bx chunk) x (all by) decode. gx%8==0, nwg%8==0.
  int gx = gridDim.x, gy = gridDim.y;
  int bid = blockIdx.y * gx + blockIdx.x;
  int cpx = (gx*gy) >> 3;
  int swz = (bid & 7) * cpx + (bid >> 3);
  int chunk = swz / (gy << 3);
  int rr = swz % (gy << 3);
  int by = rr >> 3, bx = (chunk << 3) + (rr & 7);
  int R0 = by*128, C0 = bx*128;
  const int kz = blockIdx.z;
  const bf16* Ab = A  + (size_t)kz*Ksub;
  const bf16* Bb = Bt + (size_t)kz*Ksub;
  const int KT = Ksub >> 5;

  auto stage = [&](int buf, int kt){
    #pragma unroll
    for (int is=0; is<2; ++is){
      int cc = is*256 + tid;
      int row = cc>>2, ch = cc&3;
      int chS = ch ^ ((row>>1)&3);            // source-side XOR (involution w/ read)
      gload16(Ab + (size_t)(R0+row)*lda + kt*32 + chS*8, &As[buf][cc*8]);
      gload16(Bb + (size_t)(C0+row)*ldb + kt*32 + chS*8, &Bs[buf][cc*8]);
    }
  };

  const f32x4 fz = {0.f,0.f,0.f,0.f};
  f32x4 acc[4][4];
  #pragma unroll
  for (int m=0;m<4;m++)
    #pragma unroll
    for (int n=0;n<4;n++) acc[m][n] = fz;

  int r16 = lane&15, g = lane>>4;
  int slot = (g ^ ((r16>>1)&3)) * 8;          // element offset of 16B slot
  int aoff = (wr*64 + r16)*32 + slot;
  int boff = (wc*64 + r16)*32 + slot;

  stage(0,0);
  int cur = 0;
  for (int kt=0; kt<KT; ++kt){
    __syncthreads();
    if (kt+1 < KT) stage(cur^1, kt+1);
    short8 af[4], bfr[4];
    #pragma unroll
    for (int m=0;m<4;m++)
      af[m] = *reinterpret_cast<const short8*>(&As[cur][aoff + m*512]);
    #pragma unroll
    for (int n=0;n<4;n++)
      bfr[n] = *reinterpret_cast<const short8*>(&Bs[cur][boff + n*512]);
    #pragma unroll
    for (int m=0;m<4;m++)
      #pragma unroll
      for (int n=0;n<4;n++)
        acc[m][n] = __builtin_amdgcn_mfma_f32_16x16x32_bf16(af[m], bfr[n], acc[m][n], 0,0,0);
    cur ^= 1;
  }

  // epilogue (verified r1 C/D mapping)
  int sel = C0 >> 10;
  const float* bp = QKV3 ? (sel==0 ? b0 : (sel==1 ? b1v : b2v)) : b0;
  int cb0 = QKV3 ? (C0 & 1023) : C0;
  int ab = (EPI==2) ? (kz==0) : 1;
  #pragma unroll
  for (int m=0;m<4;m++){
    #pragma unroll
    for (int n=0;n<4;n++){
      int colrel = (C0 & 1023)*0 + wc*64 + n*16 + r16;   // relative within tile
      int col = C0 + colrel;
      float bb = ab ? bp[cb0 + colrel] : 0.f;
      #pragma unroll
      for (int r=0;r<4;r++){
        int row = R0 + wr*64 + m*16 + g*4 + r;
        float vv = acc[m][n][r] + bb;
        if (EPI==0){
          ((bf16*)outp)[(size_t)row*N + col] = __float2bfloat16(vv);
        } else if (EPI==1){
          float gl = 0.5f*vv*(1.0f + erff(vv*0.70710678118654752f));
          ((bf16*)outp)[(size_t)row*N + col] = __float2bfloat16(gl);
        } else {
          ((bf16*)outp)[(size_t)kz*M_*N + (size_t)row*N + col] = __float2bfloat16(vv);
        }
      }
    }
  }
}

// ---------------- Flash attention: K direct from global (L2-hit), V staged in LDS ----------------
__global__ __launch_bounds__(512,4) void attn_k(const bf16* __restrict__ qkv,
    bf16* __restrict__ y)
{
  __shared__ bf16 Vs[T_*64];   // 64 KB, shifted-slot rows
  const int SQ = 3*C_;
  int tid = threadIdx.x, lane = tid&63, w = tid>>6;
  int b = blockIdx.z, h = blockIdx.y, qt = blockIdx.x;
  size_t baseQ = ((size_t)b*T_)*SQ + (size_t)h*64;
  size_t baseK = baseQ + 1024;
  size_t baseV = baseQ + 2048;
  size_t baseY = ((size_t)b*T_)*C_ + (size_t)h*64;

  #pragma unroll
  for (int i=0;i<8;i++){
    int cc = i*512 + tid;
    int row = cc>>3, ch = cc&7;
    short8 vv = *reinterpret_cast<const short8*>(qkv + baseV + (size_t)row*SQ + ch*8);
    int slotV = (ch + 2*((row>>3)&3)) & 7;
    *reinterpret_cast<short8*>((char*)Vs + row*128 + slotV*16) = vv;
  }
  __syncthreads();

  int g = lane>>4, r16 = lane&15;
  int qrow0 = qt*256 + w*32;
  short8 qf[2][2];
  #pragma unroll
  for (int s=0;s<2;s++)
    #pragma unroll
    for (int c=0;c<2;c++)
      qf[s][c] = *reinterpret_cast<const short8*>(qkv + baseQ + (size_t)(qrow0 + s*16 + r16)*SQ + c*32 + g*8);

  const f32x4 fz = {0.f,0.f,0.f,0.f};
  float mreg[2] = {-1e30f, -1e30f};
  float lsum[2] = {0.f, 0.f};
  f32x4 yacc[2][4];
  #pragma unroll
  for (int s=0;s<2;s++)
    #pragma unroll
    for (int dt=0;dt<4;dt++) yacc[s][dt] = fz;

  const float SC = 0.18033688011112043f; // (1/sqrt(64)) * log2(e)
  int rl0 = ((r16>>2)<<3) + (r16&3);     // k-row permutation so PV B-frag is lane-local
  const bf16* kb = qkv + baseK;

  for (int kt=0; kt<16; ++kt){
    int rowA = kt*32 + rl0;
    int rowB = rowA + 4;
    short8 kf0[2], kf1[2];
    #pragma unroll
    for (int c=0;c<2;c++){
      kf0[c] = *reinterpret_cast<const short8*>(kb + (size_t)rowA*SQ + c*32 + g*8);
      kf1[c] = *reinterpret_cast<const short8*>(kb + (size_t)rowB*SQ + c*32 + g*8);
    }
    short8 pf[2];
    #pragma unroll
    for (int s=0;s<2;s++){
      f32x4 st0 = fz, st1 = fz;
      st0 = __builtin_amdgcn_mfma_f32_16x16x32_bf16(kf0[0], qf[s][0], st0, 0,0,0);
      st0 = __builtin_amdgcn_mfma_f32_16x16x32_bf16(kf0[1], qf[s][1], st0, 0,0,0);
      st1 = __builtin_amdgcn_mfma_f32_16x16x32_bf16(kf1[0], qf[s][0], st1, 0,0,0);
      st1 = __builtin_amdgcn_mfma_f32_16x16x32_bf16(kf1[1], qf[s][1], st1, 0,0,0);
      float p0[4], p1[4];
      float tm = -1e30f;
      #pragma unroll
      for (int r=0;r<4;r++){
        p0[r] = st0[r]*SC; p1[r] = st1[r]*SC;
        tm = fmaxf(tm, fmaxf(p0[r], p1[r]));
      }
      tm = fmaxf(tm, __shfl_xor(tm, 16));
      tm = fmaxf(tm, __shfl_xor(tm, 32));
      float nm = fmaxf(mreg[s], tm);
      float f = exp2f(mreg[s] - nm);
      mreg[s] = nm;
      float psum = 0.f;
      #pragma unroll
      for (int r=0;r<4;r++){
        p0[r] = exp2f(p0[r]-nm); p1[r] = exp2f(p1[r]-nm);
        psum += p0[r] + p1[r];
      }
      lsum[s] = lsum[s]*f + psum;
      #pragma unroll
      for (int dt=0;dt<4;dt++) yacc[s][dt] *= f;
      short8 pp;
      pp[0]=f2bs(p0[0]); pp[1]=f2bs(p0[1]); pp[2]=f2bs(p0[2]); pp[3]=f2bs(p0[3]);
      pp[4]=f2bs(p1[0]); pp[5]=f2bs(p1[1]); pp[6]=f2bs(p1[2]); pp[7]=f2bs(p1[3]);
      pf[s] = pp;
    }
    #pragma unroll
    for (int dt=0;dt<4;dt++){
      short8 vfdt;
      #pragma unroll
      for (int j=0;j<8;j++){
        int row = kt*32 + g*8 + j;
        int col = dt*16 + r16;
        int slot = ((col>>3) + 2*((row>>3)&3)) & 7;
        vfdt[j] = *reinterpret_cast<const short*>((char*)Vs + row*128 + slot*16 + (col&7)*2);
      }
      yacc[0][dt] = __builtin_amdgcn_mfma_f32_16x16x32_bf16(vfdt, pf[0], yacc[0][dt], 0,0,0);
      yacc[1][dt] = __builtin_amdgcn_mfma_f32_16x16x32_bf16(vfdt, pf[1], yacc[1][dt], 0,0,0);
    }
  }

  #pragma unroll
  for (int s=0;s<2;s++){
    float ls = lsum[s];
    ls += __shfl_xor(ls, 16);
    ls += __shfl_xor(ls, 32);
    float inv = 1.0f/ls;
    int qrow = qrow0 + s*16 + r16;
    #pragma unroll
    for (int dt=0;dt<4;dt++){
      ushort4 o;
      o.x = (unsigned short)f2bs(yacc[s][dt][0]*inv);
      o.y = (unsigned short)f2bs(yacc[s][dt][1]*inv);
      o.z = (unsigned short)f2bs(yacc[s][dt][2]*inv);
      o.w = (unsigned short)f2bs(yacc[s][dt][3]*inv);
      *reinterpret_cast<ushort4*>(y + baseY + (size_t)qrow*C_ + dt*16 + g*4) = o;
    }
  }
}

// ---------------- final LN (last token only, + W2 bf16 partials) + pooling head ----------------
__global__ __launch_bounds__(256) void head_k(const float* __restrict__ hbuf,
    const bf16* __restrict__ p0, const bf16* __restrict__ p1,
    const float* __restrict__ gf, const float* __restrict__ bfv,
    const float* __restrict__ Wp, const float* __restrict__ bp, float* __restrict__ out)
{
  int b = blockIdx.x, kc = blockIdx.y, tid = threadIdx.x;
  int w = tid >> 6, lane = tid & 63;
  size_t base = ((size_t)(b*T_ + T_-1))*C_;
  float4 v = reinterpret_cast<const float4*>(hbuf + base)[tid];
  ushort4 a = reinterpret_cast<const ushort4*>(p0 + base)[tid];
  ushort4 c = reinterpret_cast<const ushort4*>(p1 + base)[tid];
  v.x += bs2f(a.x) + bs2f(c.x); v.y += bs2f(a.y) + bs2f(c.y);
  v.z += bs2f(a.z) + bs2f(c.z); v.w += bs2f(a.w) + bs2f(c.w);
  float s = v.x+v.y+v.z+v.w;
  float ss = v.x*v.x+v.y*v.y+v.z*v.z+v.w*v.w;
  #pragma unroll
  for (int o=32;o>=1;o>>=1){ s += __shfl_xor(s,o); ss += __shfl_xor(ss,o); }
  __shared__ float sa[4], sb[4];
  if (lane==0){ sa[w]=s; sb[w]=ss; }
  __syncthreads();
  s  = sa[0]+sa[1]+sa[2]+sa[3];
  ss = sb[0]+sb[1]+sb[2]+sb[3];
  float mean = s * (1.0f/C_);
  float var  = ss * (1.0f/C_) - mean*mean;
  float rs = rsqrtf(var + 1e-5f);
  __shared__ float nrm[C_];
  float4 gv = reinterpret_cast<const float4*>(gf)[tid];
  float4 bv = reinterpret_cast<const float4*>(bfv)[tid];
  nrm[tid*4+0] = (v.x-mean)*rs*gv.x + bv.x;
  nrm[tid*4+1] = (v.y-mean)*rs*gv.y + bv.y;
  nrm[tid*4+2] = (v.z-mean)*rs*gv.z + bv.z;
  nrm[tid*4+3] = (v.w-mean)*rs*gv.w + bv.w;
  __syncthreads();
  float acc = (kc==0) ? bp[tid] : 0.f;
  int k0 = kc*64;
  #pragma unroll 8
  for (int kk=k0; kk<k0+64; kk++) acc += nrm[kk]*Wp[(size_t)kk*256 + tid];
  atomicAdd(&out[b*256 + tid], acc);
}

extern "C" void kernel_launch(void* const* d_in, const int* in_sizes, int n_in,
                              void* d_out, int out_size, void* d_ws, size_t ws_size,
                              hipStream_t stream)
{
  const float* x  = (const float*)d_in[0];
  const float* Wq = (const float*)d_in[1];
  const float* bq = (const float*)d_in[2];
  const float* Wk = (const float*)d_in[3];
  const float* bk = (const float*)d_in[4];
  const float* Wv = (const float*)d_in[5];
  const float* bv = (const float*)d_in[6];
  const float* Wo = (const float*)d_in[7];
  const float* bo = (const float*)d_in[8];
  const float* g1 = (const float*)d_in[9];
  const float* be1= (const float*)d_in[10];
  const float* g2 = (const float*)d_in[11];
  const float* be2= (const float*)d_in[12];
  const float* W1 = (const float*)d_in[13];
  const float* b1 = (const float*)d_in[14];
  const float* W2 = (const float*)d_in[15];
  const float* b2 = (const float*)d_in[16];
  const float* gf = (const float*)d_in[17];
  const float* bfv= (const float*)d_in[18];
  const float* Wp = (const float*)d_in[19];
  const float* bp = (const float*)d_in[20];
  float* out = (float*)d_out;

  const size_t NEED = 209715200;
  if (ws_size < NEED) return;

  char* ws = (char*)d_ws;
  float* hbuf = (float*)ws;                      //   0 .. 32MiB  fp32 residual
  bf16* abuf  = (bf16*)(ws + 33554432);          //  32 .. 48MiB
  bf16* qkv   = (bf16*)(ws + 50331648);          //  48 .. 96MiB   [M,3C] (aliased by mid)
  bf16* ybuf  = (bf16*)(ws + 100663296);         //  96 ..112MiB   (aliased by mid)
  bf16* mid   = (bf16*)(ws + 50331648);          //  48 ..112MiB   [M,F]
  bf16* slab  = (bf16*)(ws + 117440512);         // 112 ..136MiB   per-layer bf16 Wt
  bf16* part  = (bf16*)(ws + 142606336);         // 136 ..168MiB   2x [M,C] bf16 split-K partials

  hipMemcpyAsync(hbuf, x, (size_t)M_*C_*sizeof(float), hipMemcpyDeviceToDevice, stream);
  hipMemsetAsync(d_out, 0, (size_t)out_size*sizeof(float), stream);

  for (int l=0; l<L_; ++l){
    size_t oCC = (size_t)l*C_*C_, oC = (size_t)l*C_;
    size_t oCF = (size_t)l*C_*F_, oF = (size_t)l*F_;
    convert_w<<<12288, 256, 0, stream>>>(Wq+oCC, Wk+oCC, Wv+oCC, Wo+oCC, W1+oCF, W2+oCF, slab);
    // ln1: fold in previous layer's W2 partials (none at l==0)
    ln_k<<<M_, 256, 0, stream>>>(hbuf, part, part + (size_t)M_*C_, l>0 ? 1:0, g1+oC, be1+oC, abuf);
    // fused QKV: [8192,1024] @ [3072,1024]^T -> [8192,3072]
    gemm_k<0,1><<<dim3(24,64), 256, 0, stream>>>(abuf, C_, slab, C_,
        bq+oC, bk+oC, bv+oC, qkv, 3*C_, C_);
    attn_k<<<dim3(2, H_, B_), 512, 0, stream>>>(qkv, ybuf);
    // Wo: split-K=2 -> bf16 partials
    gemm_k<2,0><<<dim3(8,64,2), 256, 0, stream>>>(ybuf, C_, slab + (size_t)3*C_*C_, C_,
        bo+oC, bo+oC, bo+oC, part, C_, C_/2);
    // ln2: fold in Wo partials
    ln_k<<<M_, 256, 0, stream>>>(hbuf, part, part + (size_t)M_*C_, 1, g2+oC, be2+oC, abuf);
    // W1: [8192,1024] @ [4096,1024]^T -> GELU -> [8192,4096]
    gemm_k<1,0><<<dim3(32,64), 256, 0, stream>>>(abuf, C_, slab + (size_t)4*C_*C_, C_,
        b1+oF, b1+oF, b1+oF, mid, F_, C_);
    // W2: split-K=2 -> bf16 partials (folded by next ln1 / head)
    gemm_k<2,0><<<dim3(8,64,2), 256, 0, stream>>>(mid, F_, slab + (size_t)4*C_*C_ + (size_t)C_*F_, F_,
        b2+oC, b2+oC, b2+oC, part, C_, F_/2);
  }
  head_k<<<dim3(B_,16), 256, 0, stream>>>(hbuf, part, part + (size_t)M_*C_,
      gf, bfv, Wp, bp, out);
}

// Round 11
// 2783.935 us; speedup vs baseline: 1.1328x; 1.1326x over previous
//
#include <hip/hip_runtime.h>
#include <hip/hip_bf16.h>
#include <math.h>

#define B_ 16
#define T_ 512
#define C_ 1024
#define H_ 16
#define D_ 64
#define F_ 4096
#define L_ 8
#define M_ (B_*T_)   // 8192 rows

typedef __hip_bfloat16 bf16;
typedef __attribute__((ext_vector_type(8))) short short8;
typedef __attribute__((ext_vector_type(4))) float f32x4;

__device__ __forceinline__ short f2bs(float x){
  union { __hip_bfloat16 h; short s; } u;
  u.h = __float2bfloat16(x);
  return u.s;
}
__device__ __forceinline__ float bs2f(unsigned short s){
  union { float f; unsigned u; } v; v.u = ((unsigned)s) << 16; return v.f;
}

__device__ __forceinline__ void gload16(const void* g, void* l){
  __builtin_amdgcn_global_load_lds((const __attribute__((address_space(1))) void*)g,
      (__attribute__((address_space(3))) void*)l, 16, 0, 0);
}

// ---------------- weight transpose+convert: W[K,N] f32 -> Wt[N,K] bf16 ----------------
__global__ __launch_bounds__(256) void convert_w(
    const float* __restrict__ Wq, const float* __restrict__ Wk,
    const float* __restrict__ Wv, const float* __restrict__ Wo,
    const float* __restrict__ W1, const float* __restrict__ W2,
    bf16* __restrict__ slab)
{
  __shared__ float t[32][33];
  int bid = blockIdx.x;
  const float* src; bf16* dst; int K, N, tile;
  if (bid < 4096) {
    int m = bid >> 10;
    src = (m==0)?Wq:(m==1)?Wk:(m==2)?Wv:Wo;
    dst = slab + (size_t)m*C_*C_;
    K = C_; N = C_; tile = bid & 1023;
  } else if (bid < 8192) {
    src = W1; dst = slab + (size_t)4*C_*C_; K = C_; N = F_; tile = bid - 4096;
  } else {
    src = W2; dst = slab + (size_t)4*C_*C_ + (size_t)C_*F_; K = F_; N = C_; tile = bid - 8192;
  }
  int tilesN = N >> 5;
  int tk = tile / tilesN, tn = tile % tilesN;
  int r = threadIdx.x >> 5, c = threadIdx.x & 31;
  #pragma unroll
  for (int i=0;i<4;i++)
    t[r + i*8][c] = src[(size_t)(tk*32 + r + i*8)*N + tn*32 + c];
  __syncthreads();
  #pragma unroll
  for (int i=0;i<4;i++)
    dst[(size_t)(tn*32 + r + i*8)*K + tk*32 + c] = __float2bfloat16(t[c][r + i*8]);
}

// ---------------- LayerNorm (+optional bf16 split-K partial reduction) ----------------
__global__ __launch_bounds__(256) void ln_k(float* __restrict__ h,
    const bf16* __restrict__ p0, const bf16* __restrict__ p1, int hasP,
    const float* __restrict__ g, const float* __restrict__ be, bf16* __restrict__ out)
{
  int row = blockIdx.x;
  int tid = threadIdx.x;
  int w = tid >> 6, lane = tid & 63;
  size_t base = (size_t)row*C_;
  float4 v = reinterpret_cast<const float4*>(h + base)[tid];
  if (hasP){
    ushort4 a = reinterpret_cast<const ushort4*>(p0 + base)[tid];
    ushort4 b = reinterpret_cast<const ushort4*>(p1 + base)[tid];
    v.x += bs2f(a.x) + bs2f(b.x); v.y += bs2f(a.y) + bs2f(b.y);
    v.z += bs2f(a.z) + bs2f(b.z); v.w += bs2f(a.w) + bs2f(b.w);
    reinterpret_cast<float4*>(h + base)[tid] = v;
  }
  float s = v.x+v.y+v.z+v.w;
  float ss = v.x*v.x+v.y*v.y+v.z*v.z+v.w*v.w;
  #pragma unroll
  for (int o=32;o>=1;o>>=1){ s += __shfl_xor(s,o); ss += __shfl_xor(ss,o); }
  __shared__ float sa[4], sb[4];
  if (lane==0){ sa[w]=s; sb[w]=ss; }
  __syncthreads();
  s  = sa[0]+sa[1]+sa[2]+sa[3];
  ss = sb[0]+sb[1]+sb[2]+sb[3];
  float mean = s * (1.0f/C_);
  float var  = ss * (1.0f/C_) - mean*mean;
  float rs = rsqrtf(var + 1e-5f);
  float4 gv = reinterpret_cast<const float4*>(g)[tid];
  float4 bv = reinterpret_cast<const float4*>(be)[tid];
  ushort4 o;
  o.x = (unsigned short)f2bs((v.x-mean)*rs*gv.x + bv.x);
  o.y = (unsigned short)f2bs((v.y-mean)*rs*gv.y + bv.y);
  o.z = (unsigned short)f2bs((v.z-mean)*rs*gv.z + bv.z);
  o.w = (unsigned short)f2bs((v.w-mean)*rs*gv.w + bv.w);
  reinterpret_cast<ushort4*>(out + base)[tid] = o;
}

// ---------------- 256x128 GEMM, BK=32, 8 waves, 2 blocks/CU (TLP hides barrier drain) ----------------
// m97 structure: double-buffered gload_lds staging, one __syncthreads per K-step.
// 48KB LDS + <=128 VGPR (launch_bounds(512,4)) -> 2 resident blocks/CU; inter-block wave
// overlap hides the staging drain (m114). L2-chunked block order + involution XOR swizzle
// (both verified r10: FETCH 57MB, conflicts 0). Hoisted 32-bit staging offsets (3 gload/thr).
// EPI: 0 = bf16+bias, 1 = exact-GELU bf16+bias, 2 = bf16 partial store (bias when kz==0)
template<int EPI, int QKV3>
__global__ __launch_bounds__(512,4) void gemm_k(
    const bf16* __restrict__ A, int lda,
    const bf16* __restrict__ Bt, int ldb,
    const float* __restrict__ b0, const float* __restrict__ b1v,
    const float* __restrict__ b2v,
    void* __restrict__ outp, int N, int Ksub)
{
  __shared__ bf16 As[2][256*32];   // 16KB per buffer
  __shared__ bf16 Bs[2][128*32];   //  8KB per buffer
  int tid = threadIdx.x, lane = tid&63, w = tid>>6;
  int wr = w>>1, wc = w&1;         // 4x2 wave grid; per-wave out 64x64

  // XCD-bijective swizzle, then (8-wide bx chunk) x (all by) decode. gx%8==0, nwg%8==0.
  int gx = gridDim.x, gy = gridDim.y;
  int bid = blockIdx.y * gx + blockIdx.x;
  int cpx = (gx*gy) >> 3;
  int swz = (bid & 7) * cpx + (bid >> 3);
  int chunk = swz / (gy << 3);
  int rr = swz % (gy << 3);
  int by = rr >> 3, bx = (chunk << 3) + (rr & 7);
  int R0 = by*256, C0 = bx*128;
  const int kz = blockIdx.z;
  const bf16* Ab = A  + (size_t)kz*Ksub;
  const bf16* Bb = Bt + (size_t)kz*Ksub;
  const int KT = Ksub >> 5;

  // hoisted staging addresses (source-side XOR swizzle; involution with read slot)
  const int rowS = tid >> 2, chS0 = (tid & 3) ^ ((rowS >> 1) & 3);
  const int offA0 = rowS * lda + chS0 * 8;
  const int offA1 = offA0 + (lda << 7);      // row+128: ((row+128)>>1)&3 == (row>>1)&3
  const int offB  = rowS * ldb + chS0 * 8;
  const bf16* pA = Ab + (size_t)R0 * lda;
  const bf16* pB = Bb + (size_t)C0 * ldb;

  auto stage = [&](int buf, int kt){
    const bf16* a = pA + kt*32;
    const bf16* b = pB + kt*32;
    gload16(a + offA0, &As[buf][tid*8]);
    gload16(a + offA1, &As[buf][4096 + tid*8]);
    gload16(b + offB,  &Bs[buf][tid*8]);
  };

  const f32x4 fz = {0.f,0.f,0.f,0.f};
  f32x4 acc[4][4];
  #pragma unroll
  for (int m=0;m<4;m++)
    #pragma unroll
    for (int n=0;n<4;n++) acc[m][n] = fz;

  int r16 = lane&15, g = lane>>4;
  int slot = (g ^ ((r16>>1)&3)) * 8;
  int aoff = (wr*64 + r16)*32 + slot;        // + m*512
  int boff = (wc*64 + r16)*32 + slot;        // + n*512

  stage(0,0);
  int cur = 0;
  for (int kt=0; kt<KT; ++kt){
    __syncthreads();
    if (kt+1 < KT) stage(cur^1, kt+1);
    short8 af[4], bfr[4];
    #pragma unroll
    for (int m=0;m<4;m++)
      af[m] = *reinterpret_cast<const short8*>(&As[cur][aoff + m*512]);
    #pragma unroll
    for (int n=0;n<4;n++)
      bfr[n] = *reinterpret_cast<const short8*>(&Bs[cur][boff + n*512]);
    #pragma unroll
    for (int m=0;m<4;m++)
      #pragma unroll
      for (int n=0;n<4;n++)
        acc[m][n] = __builtin_amdgcn_mfma_f32_16x16x32_bf16(af[m], bfr[n], acc[m][n], 0,0,0);
    cur ^= 1;
  }

  // epilogue (verified C/D mapping: col=lane&15 within frag, row=(lane>>4)*4+r)
  int sel = C0 >> 10;
  const float* bp = QKV3 ? (sel==0 ? b0 : (sel==1 ? b1v : b2v)) : b0;
  int cb0 = QKV3 ? (C0 & 1023) : C0;
  int ab = (EPI==2) ? (kz==0) : 1;
  #pragma unroll
  for (int m=0;m<4;m++){
    #pragma unroll
    for (int n=0;n<4;n++){
      int colrel = wc*64 + n*16 + r16;
      int col = C0 + colrel;
      float bb = ab ? bp[cb0 + colrel] : 0.f;
      #pragma unroll
      for (int r=0;r<4;r++){
        int row = R0 + wr*64 + m*16 + g*4 + r;
        float vv = acc[m][n][r] + bb;
        if (EPI==0){
          ((bf16*)outp)[(size_t)row*N + col] = __float2bfloat16(vv);
        } else if (EPI==1){
          float gl = 0.5f*vv*(1.0f + erff(vv*0.70710678118654752f));
          ((bf16*)outp)[(size_t)row*N + col] = __float2bfloat16(gl);
        } else {
          ((bf16*)outp)[(size_t)kz*M_*N + (size_t)row*N + col] = __float2bfloat16(vv);
        }
      }
    }
  }
}

// ---------------- Flash attention: K direct from global (L2-hit), V staged in LDS ----------------
__global__ __launch_bounds__(512,4) void attn_k(const bf16* __restrict__ qkv,
    bf16* __restrict__ y)
{
  __shared__ bf16 Vs[T_*64];   // 64 KB, shifted-slot rows
  const int SQ = 3*C_;
  int tid = threadIdx.x, lane = tid&63, w = tid>>6;
  int b = blockIdx.z, h = blockIdx.y, qt = blockIdx.x;
  size_t baseQ = ((size_t)b*T_)*SQ + (size_t)h*64;
  size_t baseK = baseQ + 1024;
  size_t baseV = baseQ + 2048;
  size_t baseY = ((size_t)b*T_)*C_ + (size_t)h*64;

  #pragma unroll
  for (int i=0;i<8;i++){
    int cc = i*512 + tid;
    int row = cc>>3, ch = cc&7;
    short8 vv = *reinterpret_cast<const short8*>(qkv + baseV + (size_t)row*SQ + ch*8);
    int slotV = (ch + 2*((row>>3)&3)) & 7;
    *reinterpret_cast<short8*>((char*)Vs + row*128 + slotV*16) = vv;
  }
  __syncthreads();

  int g = lane>>4, r16 = lane&15;
  int qrow0 = qt*256 + w*32;
  short8 qf[2][2];
  #pragma unroll
  for (int s=0;s<2;s++)
    #pragma unroll
    for (int c=0;c<2;c++)
      qf[s][c] = *reinterpret_cast<const short8*>(qkv + baseQ + (size_t)(qrow0 + s*16 + r16)*SQ + c*32 + g*8);

  const f32x4 fz = {0.f,0.f,0.f,0.f};
  float mreg[2] = {-1e30f, -1e30f};
  float lsum[2] = {0.f, 0.f};
  f32x4 yacc[2][4];
  #pragma unroll
  for (int s=0;s<2;s++)
    #pragma unroll
    for (int dt=0;dt<4;dt++) yacc[s][dt] = fz;

  const float SC = 0.18033688011112043f; // (1/sqrt(64)) * log2(e)
  int rl0 = ((r16>>2)<<3) + (r16&3);     // k-row permutation so PV B-frag is lane-local
  const bf16* kb = qkv + baseK;

  for (int kt=0; kt<16; ++kt){
    int rowA = kt*32 + rl0;
    int rowB = rowA + 4;
    short8 kf0[2], kf1[2];
    #pragma unroll
    for (int c=0;c<2;c++){
      kf0[c] = *reinterpret_cast<const short8*>(kb + (size_t)rowA*SQ + c*32 + g*8);
      kf1[c] = *reinterpret_cast<const short8*>(kb + (size_t)rowB*SQ + c*32 + g*8);
    }
    short8 pf[2];
    #pragma unroll
    for (int s=0;s<2;s++){
      f32x4 st0 = fz, st1 = fz;
      st0 = __builtin_amdgcn_mfma_f32_16x16x32_bf16(kf0[0], qf[s][0], st0, 0,0,0);
      st0 = __builtin_amdgcn_mfma_f32_16x16x32_bf16(kf0[1], qf[s][1], st0, 0,0,0);
      st1 = __builtin_amdgcn_mfma_f32_16x16x32_bf16(kf1[0], qf[s][0], st1, 0,0,0);
      st1 = __builtin_amdgcn_mfma_f32_16x16x32_bf16(kf1[1], qf[s][1], st1, 0,0,0);
      float p0[4], p1[4];
      float tm = -1e30f;
      #pragma unroll
      for (int r=0;r<4;r++){
        p0[r] = st0[r]*SC; p1[r] = st1[r]*SC;
        tm = fmaxf(tm, fmaxf(p0[r], p1[r]));
      }
      tm = fmaxf(tm, __shfl_xor(tm, 16));
      tm = fmaxf(tm, __shfl_xor(tm, 32));
      float nm = fmaxf(mreg[s], tm);
      float f = exp2f(mreg[s] - nm);
      mreg[s] = nm;
      float psum = 0.f;
      #pragma unroll
      for (int r=0;r<4;r++){
        p0[r] = exp2f(p0[r]-nm); p1[r] = exp2f(p1[r]-nm);
        psum += p0[r] + p1[r];
      }
      lsum[s] = lsum[s]*f + psum;
      #pragma unroll
      for (int dt=0;dt<4;dt++) yacc[s][dt] *= f;
      short8 pp;
      pp[0]=f2bs(p0[0]); pp[1]=f2bs(p0[1]); pp[2]=f2bs(p0[2]); pp[3]=f2bs(p0[3]);
      pp[4]=f2bs(p1[0]); pp[5]=f2bs(p1[1]); pp[6]=f2bs(p1[2]); pp[7]=f2bs(p1[3]);
      pf[s] = pp;
    }
    #pragma unroll
    for (int dt=0;dt<4;dt++){
      short8 vfdt;
      #pragma unroll
      for (int j=0;j<8;j++){
        int row = kt*32 + g*8 + j;
        int col = dt*16 + r16;
        int slot = ((col>>3) + 2*((row>>3)&3)) & 7;
        vfdt[j] = *reinterpret_cast<const short*>((char*)Vs + row*128 + slot*16 + (col&7)*2);
      }
      yacc[0][dt] = __builtin_amdgcn_mfma_f32_16x16x32_bf16(vfdt, pf[0], yacc[0][dt], 0,0,0);
      yacc[1][dt] = __builtin_amdgcn_mfma_f32_16x16x32_bf16(vfdt, pf[1], yacc[1][dt], 0,0,0);
    }
  }

  #pragma unroll
  for (int s=0;s<2;s++){
    float ls = lsum[s];
    ls += __shfl_xor(ls, 16);
    ls += __shfl_xor(ls, 32);
    float inv = 1.0f/ls;
    int qrow = qrow0 + s*16 + r16;
    #pragma unroll
    for (int dt=0;dt<4;dt++){
      ushort4 o;
      o.x = (unsigned short)f2bs(yacc[s][dt][0]*inv);
      o.y = (unsigned short)f2bs(yacc[s][dt][1]*inv);
      o.z = (unsigned short)f2bs(yacc[s][dt][2]*inv);
      o.w = (unsigned short)f2bs(yacc[s][dt][3]*inv);
      *reinterpret_cast<ushort4*>(y + baseY + (size_t)qrow*C_ + dt*16 + g*4) = o;
    }
  }
}

// ---------------- final LN (last token only, + W2 bf16 partials) + pooling head ----------------
__global__ __launch_bounds__(256) void head_k(const float* __restrict__ hbuf,
    const bf16* __restrict__ p0, const bf16* __restrict__ p1,
    const float* __restrict__ gf, const float* __restrict__ bfv,
    const float* __restrict__ Wp, const float* __restrict__ bp, float* __restrict__ out)
{
  int b = blockIdx.x, kc = blockIdx.y, tid = threadIdx.x;
  int w = tid >> 6, lane = tid & 63;
  size_t base = ((size_t)(b*T_ + T_-1))*C_;
  float4 v = reinterpret_cast<const float4*>(hbuf + base)[tid];
  ushort4 a = reinterpret_cast<const ushort4*>(p0 + base)[tid];
  ushort4 c = reinterpret_cast<const ushort4*>(p1 + base)[tid];
  v.x += bs2f(a.x) + bs2f(c.x); v.y += bs2f(a.y) + bs2f(c.y);
  v.z += bs2f(a.z) + bs2f(c.z); v.w += bs2f(a.w) + bs2f(c.w);
  float s = v.x+v.y+v.z+v.w;
  float ss = v.x*v.x+v.y*v.y+v.z*v.z+v.w*v.w;
  #pragma unroll
  for (int o=32;o>=1;o>>=1){ s += __shfl_xor(s,o); ss += __shfl_xor(ss,o); }
  __shared__ float sa[4], sb[4];
  if (lane==0){ sa[w]=s; sb[w]=ss; }
  __syncthreads();
  s  = sa[0]+sa[1]+sa[2]+sa[3];
  ss = sb[0]+sb[1]+sb[2]+sb[3];
  float mean = s * (1.0f/C_);
  float var  = ss * (1.0f/C_) - mean*mean;
  float rs = rsqrtf(var + 1e-5f);
  __shared__ float nrm[C_];
  float4 gv = reinterpret_cast<const float4*>(gf)[tid];
  float4 bv = reinterpret_cast<const float4*>(bfv)[tid];
  nrm[tid*4+0] = (v.x-mean)*rs*gv.x + bv.x;
  nrm[tid*4+1] = (v.y-mean)*rs*gv.y + bv.y;
  nrm[tid*4+2] = (v.z-mean)*rs*gv.z + bv.z;
  nrm[tid*4+3] = (v.w-mean)*rs*gv.w + bv.w;
  __syncthreads();
  float acc = (kc==0) ? bp[tid] : 0.f;
  int k0 = kc*64;
  #pragma unroll 8
  for (int kk=k0; kk<k0+64; kk++) acc += nrm[kk]*Wp[(size_t)kk*256 + tid];
  atomicAdd(&out[b*256 + tid], acc);
}

extern "C" void kernel_launch(void* const* d_in, const int* in_sizes, int n_in,
                              void* d_out, int out_size, void* d_ws, size_t ws_size,
                              hipStream_t stream)
{
  const float* x  = (const float*)d_in[0];
  const float* Wq = (const float*)d_in[1];
  const float* bq = (const float*)d_in[2];
  const float* Wk = (const float*)d_in[3];
  const float* bk = (const float*)d_in[4];
  const float* Wv = (const float*)d_in[5];
  const float* bv = (const float*)d_in[6];
  const float* Wo = (const float*)d_in[7];
  const float* bo = (const float*)d_in[8];
  const float* g1 = (const float*)d_in[9];
  const float* be1= (const float*)d_in[10];
  const float* g2 = (const float*)d_in[11];
  const float* be2= (const float*)d_in[12];
  const float* W1 = (const float*)d_in[13];
  const float* b1 = (const float*)d_in[14];
  const float* W2 = (const float*)d_in[15];
  const float* b2 = (const float*)d_in[16];
  const float* gf = (const float*)d_in[17];
  const float* bfv= (const float*)d_in[18];
  const float* Wp = (const float*)d_in[19];
  const float* bp = (const float*)d_in[20];
  float* out = (float*)d_out;

  const size_t NEED = 209715200;
  if (ws_size < NEED) return;

  char* ws = (char*)d_ws;
  float* hbuf = (float*)ws;                      //   0 .. 32MiB  fp32 residual
  bf16* abuf  = (bf16*)(ws + 33554432);          //  32 .. 48MiB
  bf16* qkv   = (bf16*)(ws + 50331648);          //  48 .. 96MiB   [M,3C] (aliased by mid)
  bf16* ybuf  = (bf16*)(ws + 100663296);         //  96 ..112MiB   (aliased by mid)
  bf16* mid   = (bf16*)(ws + 50331648);          //  48 ..112MiB   [M,F]
  bf16* slab  = (bf16*)(ws + 117440512);         // 112 ..136MiB   per-layer bf16 Wt
  bf16* part  = (bf16*)(ws + 142606336);         // 136 ..168MiB   2x [M,C] bf16 split-K partials

  hipMemcpyAsync(hbuf, x, (size_t)M_*C_*sizeof(float), hipMemcpyDeviceToDevice, stream);
  hipMemsetAsync(d_out, 0, (size_t)out_size*sizeof(float), stream);

  for (int l=0; l<L_; ++l){
    size_t oCC = (size_t)l*C_*C_, oC = (size_t)l*C_;
    size_t oCF = (size_t)l*C_*F_, oF = (size_t)l*F_;
    convert_w<<<12288, 256, 0, stream>>>(Wq+oCC, Wk+oCC, Wv+oCC, Wo+oCC, W1+oCF, W2+oCF, slab);
    // ln1: fold in previous layer's W2 partials (none at l==0)
    ln_k<<<M_, 256, 0, stream>>>(hbuf, part, part + (size_t)M_*C_, l>0 ? 1:0, g1+oC, be1+oC, abuf);
    // fused QKV: [8192,1024] @ [3072,1024]^T -> [8192,3072]
    gemm_k<0,1><<<dim3(24,32), 512, 0, stream>>>(abuf, C_, slab, C_,
        bq+oC, bk+oC, bv+oC, qkv, 3*C_, C_);
    attn_k<<<dim3(2, H_, B_), 512, 0, stream>>>(qkv, ybuf);
    // Wo: split-K=2 -> bf16 partials
    gemm_k<2,0><<<dim3(8,32,2), 512, 0, stream>>>(ybuf, C_, slab + (size_t)3*C_*C_, C_,
        bo+oC, bo+oC, bo+oC, part, C_, C_/2);
    // ln2: fold in Wo partials
    ln_k<<<M_, 256, 0, stream>>>(hbuf, part, part + (size_t)M_*C_, 1, g2+oC, be2+oC, abuf);
    // W1: [8192,1024] @ [4096,1024]^T -> GELU -> [8192,4096]
    gemm_k<1,0><<<dim3(32,32), 512, 0, stream>>>(abuf, C_, slab + (size_t)4*C_*C_, C_,
        b1+oF, b1+oF, b1+oF, mid, F_, C_);
    // W2: split-K=2 -> bf16 partials (folded by next ln1 / head)
    gemm_k<2,0><<<dim3(8,32,2), 512, 0, stream>>>(mid, F_, slab + (size_t)4*C_*C_ + (size_t)C_*F_, F_,
        b2+oC, b2+oC, b2+oC, part, C_, F_/2);
  }
  head_k<<<dim3(B_,16), 256, 0, stream>>>(hbuf, part, part + (size_t)M_*C_,
      gf, bfv, Wp, bp, out);
}

// Round 12
// 2647.781 us; speedup vs baseline: 1.1911x; 1.0514x over previous
//
#include <hip/hip_runtime.h>
#include <hip/hip_bf16.h>
#include <math.h>

#define B_ 16
#define T_ 512
#define C_ 1024
#define H_ 16
#define D_ 64
#define F_ 4096
#define L_ 8
#define M_ (B_*T_)   // 8192 rows

typedef __hip_bfloat16 bf16;
typedef __attribute__((ext_vector_type(8))) short short8;
typedef __attribute__((ext_vector_type(4))) float f32x4;

__device__ __forceinline__ short f2bs(float x){
  union { __hip_bfloat16 h; short s; } u;
  u.h = __float2bfloat16(x);
  return u.s;
}
__device__ __forceinline__ float bs2f(unsigned short s){
  union { float f; unsigned u; } v; v.u = ((unsigned)s) << 16; return v.f;
}

__device__ __forceinline__ void gload16(const void* g, void* l){
  __builtin_amdgcn_global_load_lds((const __attribute__((address_space(1))) void*)g,
      (__attribute__((address_space(3))) void*)l, 16, 0, 0);
}

// ---------------- weight transpose+convert: W[K,N] f32 -> Wt[N,K] bf16 ----------------
__global__ __launch_bounds__(256) void convert_w(
    const float* __restrict__ Wq, const float* __restrict__ Wk,
    const float* __restrict__ Wv, const float* __restrict__ Wo,
    const float* __restrict__ W1, const float* __restrict__ W2,
    bf16* __restrict__ slab)
{
  __shared__ float t[32][33];
  int bid = blockIdx.x;
  const float* src; bf16* dst; int K, N, tile;
  if (bid < 4096) {
    int m = bid >> 10;
    src = (m==0)?Wq:(m==1)?Wk:(m==2)?Wv:Wo;
    dst = slab + (size_t)m*C_*C_;
    K = C_; N = C_; tile = bid & 1023;
  } else if (bid < 8192) {
    src = W1; dst = slab + (size_t)4*C_*C_; K = C_; N = F_; tile = bid - 4096;
  } else {
    src = W2; dst = slab + (size_t)4*C_*C_ + (size_t)C_*F_; K = F_; N = C_; tile = bid - 8192;
  }
  int tilesN = N >> 5;
  int tk = tile / tilesN, tn = tile % tilesN;
  int r = threadIdx.x >> 5, c = threadIdx.x & 31;
  #pragma unroll
  for (int i=0;i<4;i++)
    t[r + i*8][c] = src[(size_t)(tk*32 + r + i*8)*N + tn*32 + c];
  __syncthreads();
  #pragma unroll
  for (int i=0;i<4;i++)
    dst[(size_t)(tn*32 + r + i*8)*K + tk*32 + c] = __float2bfloat16(t[c][r + i*8]);
}

// ---------------- LayerNorm (+optional bf16 split-K partial reduction) ----------------
__global__ __launch_bounds__(256) void ln_k(float* __restrict__ h,
    const bf16* __restrict__ p0, const bf16* __restrict__ p1, int hasP,
    const float* __restrict__ g, const float* __restrict__ be, bf16* __restrict__ out)
{
  int row = blockIdx.x;
  int tid = threadIdx.x;
  int w = tid >> 6, lane = tid & 63;
  size_t base = (size_t)row*C_;
  float4 v = reinterpret_cast<const float4*>(h + base)[tid];
  if (hasP){
    ushort4 a = reinterpret_cast<const ushort4*>(p0 + base)[tid];
    ushort4 b = reinterpret_cast<const ushort4*>(p1 + base)[tid];
    v.x += bs2f(a.x) + bs2f(b.x); v.y += bs2f(a.y) + bs2f(b.y);
    v.z += bs2f(a.z) + bs2f(b.z); v.w += bs2f(a.w) + bs2f(b.w);
    reinterpret_cast<float4*>(h + base)[tid] = v;
  }
  float s = v.x+v.y+v.z+v.w;
  float ss = v.x*v.x+v.y*v.y+v.z*v.z+v.w*v.w;
  #pragma unroll
  for (int o=32;o>=1;o>>=1){ s += __shfl_xor(s,o); ss += __shfl_xor(ss,o); }
  __shared__ float sa[4], sb[4];
  if (lane==0){ sa[w]=s; sb[w]=ss; }
  __syncthreads();
  s  = sa[0]+sa[1]+sa[2]+sa[3];
  ss = sb[0]+sb[1]+sb[2]+sb[3];
  float mean = s * (1.0f/C_);
  float var  = ss * (1.0f/C_) - mean*mean;
  float rs = rsqrtf(var + 1e-5f);
  float4 gv = reinterpret_cast<const float4*>(g)[tid];
  float4 bv = reinterpret_cast<const float4*>(be)[tid];
  ushort4 o;
  o.x = (unsigned short)f2bs((v.x-mean)*rs*gv.x + bv.x);
  o.y = (unsigned short)f2bs((v.y-mean)*rs*gv.y + bv.y);
  o.z = (unsigned short)f2bs((v.z-mean)*rs*gv.z + bv.z);
  o.w = (unsigned short)f2bs((v.w-mean)*rs*gv.w + bv.w);
  reinterpret_cast<ushort4*>(out + base)[tid] = o;
}

// ---------------- 256x256 GEMM, fat 2-phase/K-tile, counted vmcnt (r7 best config) ----------------
// EPI: 0 = bf16+bias, 1 = tanh-GELU bf16+bias, 2 = bf16 partial store (+bias when kz==0)
template<int EPI, int QKV3>
__global__ __launch_bounds__(512,1) void gemm8_k(
    const bf16* __restrict__ A, int lda,
    const bf16* __restrict__ Bt, int ldb,
    const float* __restrict__ b0, const float* __restrict__ b1v,
    const float* __restrict__ b2v, int addbias,
    void* __restrict__ outp, int N, int Ksub)
{
  __shared__ char lds[131072];
  // slot byte offsets: Ae=0, Be=32768, Ao=65536, Bo=98304; halves at +0/+16384

  const int tid = threadIdx.x, lane = tid & 63;
  const int w = tid >> 6, wr = w >> 2, wc = w & 3;
  const int r16 = lane & 15, g = lane >> 4, l7 = lane & 7;

  // bijective XCD swizzle (all grids here have nwg % 8 == 0)
  int bid = blockIdx.y * gridDim.x + blockIdx.x;
  int cpx = (gridDim.x * gridDim.y) >> 3;
  int swz = (bid & 7) * cpx + (bid >> 3);
  int tn = swz % gridDim.x, tm = swz / gridDim.x;
  const int R0 = tm * 256, C0 = tn * 256;
  const int kz = blockIdx.z;
  const bf16* Ab = A  + (size_t)kz * Ksub;
  const bf16* Bb = Bt + (size_t)kz * Ksub;
  const int KT = Ksub >> 6;   // even, >= 4

  // staging: scalar row-bases + per-lane 32-bit offset (source-side XOR swizzle)
  const int rS = tid >> 3;
  const int cS = (tid & 7) ^ (rS & 7);
  const int offLa = rS * lda + cS * 8;
  const int offLb = rS * ldb + cS * 8;
  const int ld64a = lda << 6, ld64b = ldb << 6;
  const bf16* pA0 = Ab + (size_t)R0 * lda;
  const bf16* pA1 = pA0 + ((size_t)lda << 7);
  const bf16* pB0 = Bb + (size_t)C0 * ldb;
  const bf16* pB1 = pB0 + ((size_t)ldb << 7);

#define STG(slotOff, pb, ld64, offv, tile) { \
    int ut_ = (tile) < KT ? (tile) : KT-1; \
    const bf16* q_ = (pb) + (size_t)(ut_ << 6); \
    gload16(q_ + (offv), &lds[(slotOff) + tid*16]); \
    gload16(q_ + (offv) + (ld64), &lds[(slotOff) + 8192 + tid*16]); }

  // LDS read offsets (XOR swizzle folded in); all reads: &lds[const + off]
  int aOff[2], bOff[2];
  #pragma unroll
  for (int k=0;k<2;k++){
    int cl = ((((k<<2)+g) ^ l7) << 4);
    aOff[k] = ((wr*64 + r16) << 7) + cl;
    bOff[k] = ((wc*32 + r16) << 7) + cl;
  }

  // prologue: tile0 [Be0,Ae0,Be1,Ae1], tile1 [Bo0,Ao0]  (12 loads)
  STG(32768,       pB0, ld64b, offLb, 0)
  STG(0,           pA0, ld64a, offLa, 0)
  STG(32768+16384, pB1, ld64b, offLb, 0)
  STG(16384,       pA1, ld64a, offLa, 0)
  STG(98304,       pB0, ld64b, offLb, 1)
  STG(65536,       pA0, ld64a, offLa, 1)
  asm volatile("s_waitcnt vmcnt(6)" ::: "memory");
  __builtin_amdgcn_s_barrier();

  const f32x4 fz = {0.f,0.f,0.f,0.f};
  f32x4 acc[8][4];
  #pragma unroll
  for (int m=0;m<8;m++){
    #pragma unroll
    for (int n=0;n<4;n++) acc[m][n] = fz;
  }

  short8 af[4][2];        // current A half-quadrant frags
  short8 bA[2][2][2];     // full B set for current K-tile: [nh][n][k]

#define LOADA(mh, EO) { \
    _Pragma("unroll") \
    for (int m=0;m<4;m++){ \
      _Pragma("unroll") \
      for (int k=0;k<2;k++) \
        af[m][k] = *reinterpret_cast<const short8*>(&lds[(EO) + (mh)*16384 + m*2048 + aOff[k]]); } }
#define LOADBALL(EO) { \
    _Pragma("unroll") \
    for (int nh=0;nh<2;nh++){ \
      _Pragma("unroll") \
      for (int n=0;n<2;n++){ \
        _Pragma("unroll") \
        for (int k=0;k<2;k++) \
          bA[nh][n][k] = *reinterpret_cast<const short8*>(&lds[32768 + (EO) + nh*16384 + n*2048 + bOff[k]]); } } }
// 32 MFMA, k-outer so the k=0/k=1 dependent pairs are 16 apart
#define MM2(mh) { \
    __builtin_amdgcn_s_setprio(1); \
    _Pragma("unroll") \
    for (int k=0;k<2;k++){ \
      _Pragma("unroll") \
      for (int m=0;m<4;m++){ \
        _Pragma("unroll") \
        for (int nh=0;nh<2;nh++){ \
          _Pragma("unroll") \
          for (int n=0;n<2;n++) \
            acc[(mh)*4+m][nh*2+n] = __builtin_amdgcn_mfma_f32_16x16x32_bf16( \
                af[m][k], bA[nh][n][k], acc[(mh)*4+m][nh*2+n], 0,0,0); } } } \
    __builtin_amdgcn_s_setprio(0); }
#define BAR __builtin_amdgcn_s_barrier()
#define WV8 asm volatile("s_waitcnt vmcnt(8)" ::: "memory")
#define WV6 asm volatile("s_waitcnt vmcnt(6)" ::: "memory")

  for (int it=0; it<KT/2; ++it){
    int u = 2*it;
    // phA even: A-h0 + B-all of tile u; stage [Bo1,Ao1] <- u+1
    LOADA(0,0) LOADBALL(0)
    STG(98304+16384, pB1, ld64b, offLb, u+1)
    STG(65536+16384, pA1, ld64a, offLa, u+1)
    BAR; MM2(0) WV8; BAR;
    // phB even: A-h1 of tile u; stage [Be0,Ae0] <- u+2
    LOADA(1,0)
    STG(32768,       pB0, ld64b, offLb, u+2)
    STG(0,           pA0, ld64a, offLa, u+2)
    BAR; MM2(1) WV6; BAR;
    // phA odd: tile u+1; stage [Be1,Ae1] <- u+2
    LOADA(0,65536) LOADBALL(65536)
    STG(32768+16384, pB1, ld64b, offLb, u+2)
    STG(16384,       pA1, ld64a, offLa, u+2)
    BAR; MM2(0) WV8; BAR;
    // phB odd: stage [Bo0,Ao0] <- u+3
    LOADA(1,65536)
    STG(98304,       pB0, ld64b, offLb, u+3)
    STG(65536,       pA0, ld64a, offLa, u+3)
    BAR; MM2(1) WV6; BAR;
  }
  asm volatile("s_waitcnt vmcnt(0)" ::: "memory");
#undef LOADA
#undef LOADBALL
#undef MM2
#undef BAR
#undef WV8
#undef WV6
#undef STG

  // epilogue
  int sel = C0 >> 10;
  const float* bp = QKV3 ? (sel==0 ? b0 : (sel==1 ? b1v : b2v)) : b0;
  int cb0 = QKV3 ? (C0 & 1023) : C0;
  int ab = addbias && (kz == 0);
  #pragma unroll
  for (int mh=0; mh<2; mh++){
    #pragma unroll
    for (int m=0;m<4;m++){
      #pragma unroll
      for (int nh=0; nh<2; nh++){
        #pragma unroll
        for (int n=0;n<2;n++){
          int colrel = nh*128 + wc*32 + n*16 + r16;
          int col = C0 + colrel;
          float bb = ab ? bp[cb0 + colrel] : 0.f;
          #pragma unroll
          for (int r=0;r<4;r++){
            int row = R0 + mh*128 + wr*64 + m*16 + g*4 + r;
            float vv = acc[mh*4+m][nh*2+n][r] + bb;
            if (EPI==0){
              ((bf16*)outp)[(size_t)row*N + col] = __float2bfloat16(vv);
            } else if (EPI==1){
              float z = 0.7978845608f*(vv + 0.044715f*vv*vv*vv);
              float e = exp2f(fminf(z*2.885390082f, 80.f));
              float gl = vv * e * __builtin_amdgcn_rcpf(e + 1.0f);
              ((bf16*)outp)[(size_t)row*N + col] = __float2bfloat16(gl);
            } else {
              ((bf16*)outp)[(size_t)kz*M_*N + (size_t)row*N + col] = __float2bfloat16(vv);
            }
          }
        }
      }
    }
  }
}

// ---------------- Flash attention: K direct from global (L2-hit), V transposed in LDS ----------------
// Vt[kt][d][32] (u16), slot-swizzled: phys_slot = (tok2>>3) ^ (d&3). PV reads are ds_read_b128,
// verified conflict-free (8 classes x 8 lanes = structural min); replaces 512 scalar u16 reads/lane.
__global__ __launch_bounds__(512,4) void attn_k(const bf16* __restrict__ qkv,
    bf16* __restrict__ y)
{
  __shared__ unsigned short Vt[16*2048];   // 64 KB
  const int SQ = 3*C_;
  int tid = threadIdx.x, lane = tid&63, w = tid>>6;
  int b = blockIdx.z, h = blockIdx.y, qt = blockIdx.x;
  size_t baseQ = ((size_t)b*T_)*SQ + (size_t)h*64;
  size_t baseK = baseQ + 1024;
  size_t baseV = baseQ + 2048;
  size_t baseY = ((size_t)b*T_)*C_ + (size_t)h*64;

  #pragma unroll
  for (int i=0;i<8;i++){
    int cc = i*512 + tid;
    int tok = cc>>3, ch = cc&7;
    short8 vv = *reinterpret_cast<const short8*>(qkv + baseV + (size_t)tok*SQ + ch*8);
    int baseT = (tok>>5)*2048 + ch*256 + (tok&7);
    int ls = (tok&31)>>3;
    #pragma unroll
    for (int j=0;j<8;j++)
      Vt[baseT + j*32 + ((ls^(j&3))<<3)] = (unsigned short)vv[j];
  }
  __syncthreads();

  int g = lane>>4, r16 = lane&15;
  int qrow0 = qt*256 + w*32;
  short8 qf[2][2];
  #pragma unroll
  for (int s=0;s<2;s++)
    #pragma unroll
    for (int c=0;c<2;c++)
      qf[s][c] = *reinterpret_cast<const short8*>(qkv + baseQ + (size_t)(qrow0 + s*16 + r16)*SQ + c*32 + g*8);

  const f32x4 fz = {0.f,0.f,0.f,0.f};
  float mreg[2] = {-1e30f, -1e30f};
  float lsum[2] = {0.f, 0.f};
  f32x4 yacc[2][4];
  #pragma unroll
  for (int s=0;s<2;s++)
    #pragma unroll
    for (int dt=0;dt<4;dt++) yacc[s][dt] = fz;

  const float SC = 0.18033688011112043f; // (1/sqrt(64)) * log2(e)
  int rl0 = ((r16>>2)<<3) + (r16&3);     // k-row permutation so PV B-frag is lane-local
  const bf16* kb = qkv + baseK;
  const int vb0 = r16*32 + ((g ^ (r16&3))<<3);   // d=dt*16+r16 row base + swizzled slot

  for (int kt=0; kt<16; ++kt){
    int rowA = kt*32 + rl0;
    int rowB = rowA + 4;
    short8 kf0[2], kf1[2];
    #pragma unroll
    for (int c=0;c<2;c++){
      kf0[c] = *reinterpret_cast<const short8*>(kb + (size_t)rowA*SQ + c*32 + g*8);
      kf1[c] = *reinterpret_cast<const short8*>(kb + (size_t)rowB*SQ + c*32 + g*8);
    }
    short8 pf[2];
    #pragma unroll
    for (int s=0;s<2;s++){
      f32x4 st0 = fz, st1 = fz;
      st0 = __builtin_amdgcn_mfma_f32_16x16x32_bf16(kf0[0], qf[s][0], st0, 0,0,0);
      st0 = __builtin_amdgcn_mfma_f32_16x16x32_bf16(kf0[1], qf[s][1], st0, 0,0,0);
      st1 = __builtin_amdgcn_mfma_f32_16x16x32_bf16(kf1[0], qf[s][0], st1, 0,0,0);
      st1 = __builtin_amdgcn_mfma_f32_16x16x32_bf16(kf1[1], qf[s][1], st1, 0,0,0);
      float p0[4], p1[4];
      float tm = -1e30f;
      #pragma unroll
      for (int r=0;r<4;r++){
        p0[r] = st0[r]*SC; p1[r] = st1[r]*SC;
        tm = fmaxf(tm, fmaxf(p0[r], p1[r]));
      }
      tm = fmaxf(tm, __shfl_xor(tm, 16));
      tm = fmaxf(tm, __shfl_xor(tm, 32));
      float nm = fmaxf(mreg[s], tm);
      float f = exp2f(mreg[s] - nm);
      mreg[s] = nm;
      float psum = 0.f;
      #pragma unroll
      for (int r=0;r<4;r++){
        p0[r] = exp2f(p0[r]-nm); p1[r] = exp2f(p1[r]-nm);
        psum += p0[r] + p1[r];
      }
      lsum[s] = lsum[s]*f + psum;
      #pragma unroll
      for (int dt=0;dt<4;dt++) yacc[s][dt] *= f;
      short8 pp;
      pp[0]=f2bs(p0[0]); pp[1]=f2bs(p0[1]); pp[2]=f2bs(p0[2]); pp[3]=f2bs(p0[3]);
      pp[4]=f2bs(p1[0]); pp[5]=f2bs(p1[1]); pp[6]=f2bs(p1[2]); pp[7]=f2bs(p1[3]);
      pf[s] = pp;
    }
    #pragma unroll
    for (int dt=0;dt<4;dt++){
      short8 vfdt = *reinterpret_cast<const short8*>(&Vt[kt*2048 + dt*512 + vb0]);
      yacc[0][dt] = __builtin_amdgcn_mfma_f32_16x16x32_bf16(vfdt, pf[0], yacc[0][dt], 0,0,0);
      yacc[1][dt] = __builtin_amdgcn_mfma_f32_16x16x32_bf16(vfdt, pf[1], yacc[1][dt], 0,0,0);
    }
  }

  #pragma unroll
  for (int s=0;s<2;s++){
    float ls = lsum[s];
    ls += __shfl_xor(ls, 16);
    ls += __shfl_xor(ls, 32);
    float inv = 1.0f/ls;
    int qrow = qrow0 + s*16 + r16;
    #pragma unroll
    for (int dt=0;dt<4;dt++){
      ushort4 o;
      o.x = (unsigned short)f2bs(yacc[s][dt][0]*inv);
      o.y = (unsigned short)f2bs(yacc[s][dt][1]*inv);
      o.z = (unsigned short)f2bs(yacc[s][dt][2]*inv);
      o.w = (unsigned short)f2bs(yacc[s][dt][3]*inv);
      *reinterpret_cast<ushort4*>(y + baseY + (size_t)qrow*C_ + dt*16 + g*4) = o;
    }
  }
}

// ---------------- final LN (last token only, + W2 bf16 partials) + pooling head ----------------
__global__ __launch_bounds__(256) void head_k(const float* __restrict__ hbuf,
    const bf16* __restrict__ p0, const bf16* __restrict__ p1,
    const float* __restrict__ gf, const float* __restrict__ bfv,
    const float* __restrict__ Wp, const float* __restrict__ bp, float* __restrict__ out)
{
  int b = blockIdx.x, kc = blockIdx.y, tid = threadIdx.x;
  int w = tid >> 6, lane = tid & 63;
  size_t base = ((size_t)(b*T_ + T_-1))*C_;
  float4 v = reinterpret_cast<const float4*>(hbuf + base)[tid];
  ushort4 a = reinterpret_cast<const ushort4*>(p0 + base)[tid];
  ushort4 c = reinterpret_cast<const ushort4*>(p1 + base)[tid];
  v.x += bs2f(a.x) + bs2f(c.x); v.y += bs2f(a.y) + bs2f(c.y);
  v.z += bs2f(a.z) + bs2f(c.z); v.w += bs2f(a.w) + bs2f(c.w);
  float s = v.x+v.y+v.z+v.w;
  float ss = v.x*v.x+v.y*v.y+v.z*v.z+v.w*v.w;
  #pragma unroll
  for (int o=32;o>=1;o>>=1){ s += __shfl_xor(s,o); ss += __shfl_xor(ss,o); }
  __shared__ float sa[4], sb[4];
  if (lane==0){ sa[w]=s; sb[w]=ss; }
  __syncthreads();
  s  = sa[0]+sa[1]+sa[2]+sa[3];
  ss = sb[0]+sb[1]+sb[2]+sb[3];
  float mean = s * (1.0f/C_);
  float var  = ss * (1.0f/C_) - mean*mean;
  float rs = rsqrtf(var + 1e-5f);
  __shared__ float nrm[C_];
  float4 gv = reinterpret_cast<const float4*>(gf)[tid];
  float4 bv = reinterpret_cast<const float4*>(bfv)[tid];
  nrm[tid*4+0] = (v.x-mean)*rs*gv.x + bv.x;
  nrm[tid*4+1] = (v.y-mean)*rs*gv.y + bv.y;
  nrm[tid*4+2] = (v.z-mean)*rs*gv.z + bv.z;
  nrm[tid*4+3] = (v.w-mean)*rs*gv.w + bv.w;
  __syncthreads();
  float acc = (kc==0) ? bp[tid] : 0.f;
  int k0 = kc*64;
  #pragma unroll 8
  for (int kk=k0; kk<k0+64; kk++) acc += nrm[kk]*Wp[(size_t)kk*256 + tid];
  atomicAdd(&out[b*256 + tid], acc);
}

extern "C" void kernel_launch(void* const* d_in, const int* in_sizes, int n_in,
                              void* d_out, int out_size, void* d_ws, size_t ws_size,
                              hipStream_t stream)
{
  const float* x  = (const float*)d_in[0];
  const float* Wq = (const float*)d_in[1];
  const float* bq = (const float*)d_in[2];
  const float* Wk = (const float*)d_in[3];
  const float* bk = (const float*)d_in[4];
  const float* Wv = (const float*)d_in[5];
  const float* bv = (const float*)d_in[6];
  const float* Wo = (const float*)d_in[7];
  const float* bo = (const float*)d_in[8];
  const float* g1 = (const float*)d_in[9];
  const float* be1= (const float*)d_in[10];
  const float* g2 = (const float*)d_in[11];
  const float* be2= (const float*)d_in[12];
  const float* W1 = (const float*)d_in[13];
  const float* b1 = (const float*)d_in[14];
  const float* W2 = (const float*)d_in[15];
  const float* b2 = (const float*)d_in[16];
  const float* gf = (const float*)d_in[17];
  const float* bfv= (const float*)d_in[18];
  const float* Wp = (const float*)d_in[19];
  const float* bp = (const float*)d_in[20];
  float* out = (float*)d_out;

  const size_t NEED = 209715200;
  if (ws_size < NEED) return;

  char* ws = (char*)d_ws;
  float* hbuf = (float*)ws;                      //   0 .. 32MiB  fp32 residual
  bf16* abuf  = (bf16*)(ws + 33554432);          //  32 .. 48MiB
  bf16* qkv   = (bf16*)(ws + 50331648);          //  48 .. 96MiB   [M,3C] (aliased by mid)
  bf16* ybuf  = (bf16*)(ws + 100663296);         //  96 ..112MiB   (aliased by mid)
  bf16* mid   = (bf16*)(ws + 50331648);          //  48 ..112MiB   [M,F]
  bf16* slab  = (bf16*)(ws + 117440512);         // 112 ..136MiB   per-layer bf16 Wt
  bf16* part  = (bf16*)(ws + 142606336);         // 136 ..168MiB   2x [M,C] bf16 split-K partials

  hipMemcpyAsync(hbuf, x, (size_t)M_*C_*sizeof(float), hipMemcpyDeviceToDevice, stream);
  hipMemsetAsync(d_out, 0, (size_t)out_size*sizeof(float), stream);

  for (int l=0; l<L_; ++l){
    size_t oCC = (size_t)l*C_*C_, oC = (size_t)l*C_;
    size_t oCF = (size_t)l*C_*F_, oF = (size_t)l*F_;
    convert_w<<<12288, 256, 0, stream>>>(Wq+oCC, Wk+oCC, Wv+oCC, Wo+oCC, W1+oCF, W2+oCF, slab);
    // ln1: fold in previous layer's W2 partials (none at l==0)
    ln_k<<<M_, 256, 0, stream>>>(hbuf, part, part + (size_t)M_*C_, l>0 ? 1:0, g1+oC, be1+oC, abuf);
    // fused QKV: [8192,1024] @ [3072,1024]^T -> [8192,3072]
    gemm8_k<0,1><<<dim3(12,32), 512, 0, stream>>>(abuf, C_, slab, C_,
        bq+oC, bk+oC, bv+oC, 1, qkv, 3*C_, C_);
    attn_k<<<dim3(2, H_, B_), 512, 0, stream>>>(qkv, ybuf);
    // Wo: split-K=2 -> bf16 partials
    gemm8_k<2,0><<<dim3(4,32,2), 512, 0, stream>>>(ybuf, C_, slab + (size_t)3*C_*C_, C_,
        bo+oC, bo+oC, bo+oC, 1, part, C_, C_/2);
    // ln2: fold in Wo partials
    ln_k<<<M_, 256, 0, stream>>>(hbuf, part, part + (size_t)M_*C_, 1, g2+oC, be2+oC, abuf);
    // W1: [8192,1024] @ [4096,1024]^T -> GELU -> [8192,4096]
    gemm8_k<1,0><<<dim3(16,32), 512, 0, stream>>>(abuf, C_, slab + (size_t)4*C_*C_, C_,
        b1+oF, b1+oF, b1+oF, 1, mid, F_, C_);
    // W2: split-K=2 -> bf16 partials (folded by next ln1 / head)
    gemm8_k<2,0><<<dim3(4,32,2), 512, 0, stream>>>(mid, F_, slab + (size_t)4*C_*C_ + (size_t)C_*F_, F_,
        b2+oC, b2+oC, b2+oC, 1, part, C_, F_/2);
  }
  head_k<<<dim3(B_,16), 256, 0, stream>>>(hbuf, part, part + (size_t)M_*C_,
      gf, bfv, Wp, bp, out);
}

// Round 13
// 2558.445 us; speedup vs baseline: 1.2327x; 1.0349x over previous
//
#include <hip/hip_runtime.h>
#include <hip/hip_bf16.h>
#include <math.h>

#define B_ 16
#define T_ 512
#define C_ 1024
#define H_ 16
#define D_ 64
#define F_ 4096
#define L_ 8
#define M_ (B_*T_)   // 8192 rows

typedef __hip_bfloat16 bf16;
typedef __attribute__((ext_vector_type(8))) short short8;
typedef __attribute__((ext_vector_type(4))) float f32x4;

__device__ __forceinline__ short f2bs(float x){
  union { __hip_bfloat16 h; short s; } u;
  u.h = __float2bfloat16(x);
  return u.s;
}
__device__ __forceinline__ float bs2f(unsigned short s){
  union { float f; unsigned u; } v; v.u = ((unsigned)s) << 16; return v.f;
}

__device__ __forceinline__ void gload16(const void* g, void* l){
  __builtin_amdgcn_global_load_lds((const __attribute__((address_space(1))) void*)g,
      (__attribute__((address_space(3))) void*)l, 16, 0, 0);
}

// ---------------- x f32 -> h bf16 ----------------
__global__ __launch_bounds__(256) void cvt_x(const float* __restrict__ x, bf16* __restrict__ h){
  int i = blockIdx.x*256 + threadIdx.x;
  float4 v = reinterpret_cast<const float4*>(x)[i];
  ushort4 o;
  o.x = (unsigned short)f2bs(v.x); o.y = (unsigned short)f2bs(v.y);
  o.z = (unsigned short)f2bs(v.z); o.w = (unsigned short)f2bs(v.w);
  reinterpret_cast<ushort4*>(h)[i] = o;
}

// ---------------- weight transpose+convert: W[K,N] f32 -> Wt[N,K] bf16 ----------------
__global__ __launch_bounds__(256) void convert_w(
    const float* __restrict__ Wq, const float* __restrict__ Wk,
    const float* __restrict__ Wv, const float* __restrict__ Wo,
    const float* __restrict__ W1, const float* __restrict__ W2,
    bf16* __restrict__ slab)
{
  __shared__ float t[32][33];
  int bid = blockIdx.x;
  const float* src; bf16* dst; int K, N, tile;
  if (bid < 4096) {
    int m = bid >> 10;
    src = (m==0)?Wq:(m==1)?Wk:(m==2)?Wv:Wo;
    dst = slab + (size_t)m*C_*C_;
    K = C_; N = C_; tile = bid & 1023;
  } else if (bid < 8192) {
    src = W1; dst = slab + (size_t)4*C_*C_; K = C_; N = F_; tile = bid - 4096;
  } else {
    src = W2; dst = slab + (size_t)4*C_*C_ + (size_t)C_*F_; K = F_; N = C_; tile = bid - 8192;
  }
  int tilesN = N >> 5;
  int tk = tile / tilesN, tn = tile % tilesN;
  int r = threadIdx.x >> 5, c = threadIdx.x & 31;
  #pragma unroll
  for (int i=0;i<4;i++)
    t[r + i*8][c] = src[(size_t)(tk*32 + r + i*8)*N + tn*32 + c];
  __syncthreads();
  #pragma unroll
  for (int i=0;i<4;i++)
    dst[(size_t)(tn*32 + r + i*8)*K + tk*32 + c] = __float2bfloat16(t[c][r + i*8]);
}

// ---------------- LayerNorm on bf16 residual (+optional bf16 split-K partial fold) ----------------
// v = h + (hasP ? p0+p1 : 0) in f32; if hasP: h <- bf16(v); out = LN(v)*g+be (bf16)
__global__ __launch_bounds__(256) void ln_k(bf16* __restrict__ h,
    const bf16* __restrict__ p0, const bf16* __restrict__ p1, int hasP,
    const float* __restrict__ g, const float* __restrict__ be, bf16* __restrict__ out)
{
  int row = blockIdx.x;
  int tid = threadIdx.x;
  int w = tid >> 6, lane = tid & 63;
  size_t base = (size_t)row*C_;
  ushort4 hv = reinterpret_cast<const ushort4*>(h + base)[tid];
  float vx = bs2f(hv.x), vy = bs2f(hv.y), vz = bs2f(hv.z), vw = bs2f(hv.w);
  if (hasP){
    ushort4 a = reinterpret_cast<const ushort4*>(p0 + base)[tid];
    ushort4 b = reinterpret_cast<const ushort4*>(p1 + base)[tid];
    vx += bs2f(a.x) + bs2f(b.x); vy += bs2f(a.y) + bs2f(b.y);
    vz += bs2f(a.z) + bs2f(b.z); vw += bs2f(a.w) + bs2f(b.w);
    ushort4 hw;
    hw.x = (unsigned short)f2bs(vx); hw.y = (unsigned short)f2bs(vy);
    hw.z = (unsigned short)f2bs(vz); hw.w = (unsigned short)f2bs(vw);
    reinterpret_cast<ushort4*>(h + base)[tid] = hw;
  }
  float s = vx+vy+vz+vw;
  float ss = vx*vx+vy*vy+vz*vz+vw*vw;
  #pragma unroll
  for (int o=32;o>=1;o>>=1){ s += __shfl_xor(s,o); ss += __shfl_xor(ss,o); }
  __shared__ float sa[4], sb[4];
  if (lane==0){ sa[w]=s; sb[w]=ss; }
  __syncthreads();
  s  = sa[0]+sa[1]+sa[2]+sa[3];
  ss = sb[0]+sb[1]+sb[2]+sb[3];
  float mean = s * (1.0f/C_);
  float var  = ss * (1.0f/C_) - mean*mean;
  float rs = rsqrtf(var + 1e-5f);
  float4 gv = reinterpret_cast<const float4*>(g)[tid];
  float4 bv = reinterpret_cast<const float4*>(be)[tid];
  ushort4 o;
  o.x = (unsigned short)f2bs((vx-mean)*rs*gv.x + bv.x);
  o.y = (unsigned short)f2bs((vy-mean)*rs*gv.y + bv.y);
  o.z = (unsigned short)f2bs((vz-mean)*rs*gv.z + bv.z);
  o.w = (unsigned short)f2bs((vw-mean)*rs*gv.w + bv.w);
  reinterpret_cast<ushort4*>(out + base)[tid] = o;
}

// ---------------- 256x256 GEMM, fat 2-phase/K-tile, counted vmcnt (r7 best config) ----------------
// EPI: 0 = bf16+bias, 1 = tanh-GELU bf16+bias, 2 = bf16 partial store (+bias when kz==0)
template<int EPI, int QKV3>
__global__ __launch_bounds__(512,1) void gemm8_k(
    const bf16* __restrict__ A, int lda,
    const bf16* __restrict__ Bt, int ldb,
    const float* __restrict__ b0, const float* __restrict__ b1v,
    const float* __restrict__ b2v, int addbias,
    void* __restrict__ outp, int N, int Ksub)
{
  __shared__ char lds[131072];
  // slot byte offsets: Ae=0, Be=32768, Ao=65536, Bo=98304; halves at +0/+16384

  const int tid = threadIdx.x, lane = tid & 63;
  const int w = tid >> 6, wr = w >> 2, wc = w & 3;
  const int r16 = lane & 15, g = lane >> 4, l7 = lane & 7;

  // bijective XCD swizzle (all grids here have nwg % 8 == 0)
  int bid = blockIdx.y * gridDim.x + blockIdx.x;
  int cpx = (gridDim.x * gridDim.y) >> 3;
  int swz = (bid & 7) * cpx + (bid >> 3);
  int tn = swz % gridDim.x, tm = swz / gridDim.x;
  const int R0 = tm * 256, C0 = tn * 256;
  const int kz = blockIdx.z;
  const bf16* Ab = A  + (size_t)kz * Ksub;
  const bf16* Bb = Bt + (size_t)kz * Ksub;
  const int KT = Ksub >> 6;   // even, >= 4

  // staging: scalar row-bases + per-lane 32-bit offset (source-side XOR swizzle)
  const int rS = tid >> 3;
  const int cS = (tid & 7) ^ (rS & 7);
  const int offLa = rS * lda + cS * 8;
  const int offLb = rS * ldb + cS * 8;
  const int ld64a = lda << 6, ld64b = ldb << 6;
  const bf16* pA0 = Ab + (size_t)R0 * lda;
  const bf16* pA1 = pA0 + ((size_t)lda << 7);
  const bf16* pB0 = Bb + (size_t)C0 * ldb;
  const bf16* pB1 = pB0 + ((size_t)ldb << 7);

#define STG(slotOff, pb, ld64, offv, tile) { \
    int ut_ = (tile) < KT ? (tile) : KT-1; \
    const bf16* q_ = (pb) + (size_t)(ut_ << 6); \
    gload16(q_ + (offv), &lds[(slotOff) + tid*16]); \
    gload16(q_ + (offv) + (ld64), &lds[(slotOff) + 8192 + tid*16]); }

  // LDS read offsets (XOR swizzle folded in); all reads: &lds[const + off]
  int aOff[2], bOff[2];
  #pragma unroll
  for (int k=0;k<2;k++){
    int cl = ((((k<<2)+g) ^ l7) << 4);
    aOff[k] = ((wr*64 + r16) << 7) + cl;
    bOff[k] = ((wc*32 + r16) << 7) + cl;
  }

  // prologue: tile0 [Be0,Ae0,Be1,Ae1], tile1 [Bo0,Ao0]  (12 loads)
  STG(32768,       pB0, ld64b, offLb, 0)
  STG(0,           pA0, ld64a, offLa, 0)
  STG(32768+16384, pB1, ld64b, offLb, 0)
  STG(16384,       pA1, ld64a, offLa, 0)
  STG(98304,       pB0, ld64b, offLb, 1)
  STG(65536,       pA0, ld64a, offLa, 1)
  asm volatile("s_waitcnt vmcnt(6)" ::: "memory");
  __builtin_amdgcn_s_barrier();

  const f32x4 fz = {0.f,0.f,0.f,0.f};
  f32x4 acc[8][4];
  #pragma unroll
  for (int m=0;m<8;m++){
    #pragma unroll
    for (int n=0;n<4;n++) acc[m][n] = fz;
  }

  short8 af[4][2];        // current A half-quadrant frags
  short8 bA[2][2][2];     // full B set for current K-tile: [nh][n][k]

#define LOADA(mh, EO) { \
    _Pragma("unroll") \
    for (int m=0;m<4;m++){ \
      _Pragma("unroll") \
      for (int k=0;k<2;k++) \
        af[m][k] = *reinterpret_cast<const short8*>(&lds[(EO) + (mh)*16384 + m*2048 + aOff[k]]); } }
#define LOADBALL(EO) { \
    _Pragma("unroll") \
    for (int nh=0;nh<2;nh++){ \
      _Pragma("unroll") \
      for (int n=0;n<2;n++){ \
        _Pragma("unroll") \
        for (int k=0;k<2;k++) \
          bA[nh][n][k] = *reinterpret_cast<const short8*>(&lds[32768 + (EO) + nh*16384 + n*2048 + bOff[k]]); } } }
// 32 MFMA, k-outer so the k=0/k=1 dependent pairs are 16 apart
#define MM2(mh) { \
    __builtin_amdgcn_s_setprio(1); \
    _Pragma("unroll") \
    for (int k=0;k<2;k++){ \
      _Pragma("unroll") \
      for (int m=0;m<4;m++){ \
        _Pragma("unroll") \
        for (int nh=0;nh<2;nh++){ \
          _Pragma("unroll") \
          for (int n=0;n<2;n++) \
            acc[(mh)*4+m][nh*2+n] = __builtin_amdgcn_mfma_f32_16x16x32_bf16( \
                af[m][k], bA[nh][n][k], acc[(mh)*4+m][nh*2+n], 0,0,0); } } } \
    __builtin_amdgcn_s_setprio(0); }
#define BAR __builtin_amdgcn_s_barrier()
#define WV8 asm volatile("s_waitcnt vmcnt(8)" ::: "memory")
#define WV6 asm volatile("s_waitcnt vmcnt(6)" ::: "memory")

  for (int it=0; it<KT/2; ++it){
    int u = 2*it;
    // phA even: A-h0 + B-all of tile u; stage [Bo1,Ao1] <- u+1
    LOADA(0,0) LOADBALL(0)
    STG(98304+16384, pB1, ld64b, offLb, u+1)
    STG(65536+16384, pA1, ld64a, offLa, u+1)
    BAR; MM2(0) WV8; BAR;
    // phB even: A-h1 of tile u; stage [Be0,Ae0] <- u+2
    LOADA(1,0)
    STG(32768,       pB0, ld64b, offLb, u+2)
    STG(0,           pA0, ld64a, offLa, u+2)
    BAR; MM2(1) WV6; BAR;
    // phA odd: tile u+1; stage [Be1,Ae1] <- u+2
    LOADA(0,65536) LOADBALL(65536)
    STG(32768+16384, pB1, ld64b, offLb, u+2)
    STG(16384,       pA1, ld64a, offLa, u+2)
    BAR; MM2(0) WV8; BAR;
    // phB odd: stage [Bo0,Ao0] <- u+3
    LOADA(1,65536)
    STG(98304,       pB0, ld64b, offLb, u+3)
    STG(65536,       pA0, ld64a, offLa, u+3)
    BAR; MM2(1) WV6; BAR;
  }
  asm volatile("s_waitcnt vmcnt(0)" ::: "memory");
#undef LOADA
#undef LOADBALL
#undef MM2
#undef BAR
#undef WV8
#undef WV6
#undef STG

  // epilogue
  int sel = C0 >> 10;
  const float* bp = QKV3 ? (sel==0 ? b0 : (sel==1 ? b1v : b2v)) : b0;
  int cb0 = QKV3 ? (C0 & 1023) : C0;
  int ab = addbias && (kz == 0);
  #pragma unroll
  for (int mh=0; mh<2; mh++){
    #pragma unroll
    for (int m=0;m<4;m++){
      #pragma unroll
      for (int nh=0; nh<2; nh++){
        #pragma unroll
        for (int n=0;n<2;n++){
          int colrel = nh*128 + wc*32 + n*16 + r16;
          int col = C0 + colrel;
          float bb = ab ? bp[cb0 + colrel] : 0.f;
          #pragma unroll
          for (int r=0;r<4;r++){
            int row = R0 + mh*128 + wr*64 + m*16 + g*4 + r;
            float vv = acc[mh*4+m][nh*2+n][r] + bb;
            if (EPI==0){
              ((bf16*)outp)[(size_t)row*N + col] = __float2bfloat16(vv);
            } else if (EPI==1){
              float z = 0.7978845608f*(vv + 0.044715f*vv*vv*vv);
              float e = exp2f(fminf(z*2.885390082f, 80.f));
              float gl = vv * e * __builtin_amdgcn_rcpf(e + 1.0f);
              ((bf16*)outp)[(size_t)row*N + col] = __float2bfloat16(gl);
            } else {
              ((bf16*)outp)[(size_t)kz*M_*N + (size_t)row*N + col] = __float2bfloat16(vv);
            }
          }
        }
      }
    }
  }
}

// ---------------- Flash attention: K direct from global (L2-hit), V transposed in LDS ----------------
__global__ __launch_bounds__(512,4) void attn_k(const bf16* __restrict__ qkv,
    bf16* __restrict__ y)
{
  __shared__ unsigned short Vt[16*2048];   // 64 KB
  const int SQ = 3*C_;
  int tid = threadIdx.x, lane = tid&63, w = tid>>6;
  int b = blockIdx.z, h = blockIdx.y, qt = blockIdx.x;
  size_t baseQ = ((size_t)b*T_)*SQ + (size_t)h*64;
  size_t baseK = baseQ + 1024;
  size_t baseV = baseQ + 2048;
  size_t baseY = ((size_t)b*T_)*C_ + (size_t)h*64;

  #pragma unroll
  for (int i=0;i<8;i++){
    int cc = i*512 + tid;
    int tok = cc>>3, ch = cc&7;
    short8 vv = *reinterpret_cast<const short8*>(qkv + baseV + (size_t)tok*SQ + ch*8);
    int baseT = (tok>>5)*2048 + ch*256 + (tok&7);
    int ls = (tok&31)>>3;
    #pragma unroll
    for (int j=0;j<8;j++)
      Vt[baseT + j*32 + ((ls^(j&3))<<3)] = (unsigned short)vv[j];
  }
  __syncthreads();

  int g = lane>>4, r16 = lane&15;
  int qrow0 = qt*256 + w*32;
  short8 qf[2][2];
  #pragma unroll
  for (int s=0;s<2;s++)
    #pragma unroll
    for (int c=0;c<2;c++)
      qf[s][c] = *reinterpret_cast<const short8*>(qkv + baseQ + (size_t)(qrow0 + s*16 + r16)*SQ + c*32 + g*8);

  const f32x4 fz = {0.f,0.f,0.f,0.f};
  float mreg[2] = {-1e30f, -1e30f};
  float lsum[2] = {0.f, 0.f};
  f32x4 yacc[2][4];
  #pragma unroll
  for (int s=0;s<2;s++)
    #pragma unroll
    for (int dt=0;dt<4;dt++) yacc[s][dt] = fz;

  const float SC = 0.18033688011112043f; // (1/sqrt(64)) * log2(e)
  int rl0 = ((r16>>2)<<3) + (r16&3);     // k-row permutation so PV B-frag is lane-local
  const bf16* kb = qkv + baseK;
  const int vb0 = r16*32 + ((g ^ (r16&3))<<3);   // d=dt*16+r16 row base + swizzled slot

  for (int kt=0; kt<16; ++kt){
    int rowA = kt*32 + rl0;
    int rowB = rowA + 4;
    short8 kf0[2], kf1[2];
    #pragma unroll
    for (int c=0;c<2;c++){
      kf0[c] = *reinterpret_cast<const short8*>(kb + (size_t)rowA*SQ + c*32 + g*8);
      kf1[c] = *reinterpret_cast<const short8*>(kb + (size_t)rowB*SQ + c*32 + g*8);
    }
    short8 pf[2];
    #pragma unroll
    for (int s=0;s<2;s++){
      f32x4 st0 = fz, st1 = fz;
      st0 = __builtin_amdgcn_mfma_f32_16x16x32_bf16(kf0[0], qf[s][0], st0, 0,0,0);
      st0 = __builtin_amdgcn_mfma_f32_16x16x32_bf16(kf0[1], qf[s][1], st0, 0,0,0);
      st1 = __builtin_amdgcn_mfma_f32_16x16x32_bf16(kf1[0], qf[s][0], st1, 0,0,0);
      st1 = __builtin_amdgcn_mfma_f32_16x16x32_bf16(kf1[1], qf[s][1], st1, 0,0,0);
      float p0[4], p1[4];
      float tm = -1e30f;
      #pragma unroll
      for (int r=0;r<4;r++){
        p0[r] = st0[r]*SC; p1[r] = st1[r]*SC;
        tm = fmaxf(tm, fmaxf(p0[r], p1[r]));
      }
      tm = fmaxf(tm, __shfl_xor(tm, 16));
      tm = fmaxf(tm, __shfl_xor(tm, 32));
      float nm = fmaxf(mreg[s], tm);
      float f = exp2f(mreg[s] - nm);
      mreg[s] = nm;
      float psum = 0.f;
      #pragma unroll
      for (int r=0;r<4;r++){
        p0[r] = exp2f(p0[r]-nm); p1[r] = exp2f(p1[r]-nm);
        psum += p0[r] + p1[r];
      }
      lsum[s] = lsum[s]*f + psum;
      #pragma unroll
      for (int dt=0;dt<4;dt++) yacc[s][dt] *= f;
      short8 pp;
      pp[0]=f2bs(p0[0]); pp[1]=f2bs(p0[1]); pp[2]=f2bs(p0[2]); pp[3]=f2bs(p0[3]);
      pp[4]=f2bs(p1[0]); pp[5]=f2bs(p1[1]); pp[6]=f2bs(p1[2]); pp[7]=f2bs(p1[3]);
      pf[s] = pp;
    }
    #pragma unroll
    for (int dt=0;dt<4;dt++){
      short8 vfdt = *reinterpret_cast<const short8*>(&Vt[kt*2048 + dt*512 + vb0]);
      yacc[0][dt] = __builtin_amdgcn_mfma_f32_16x16x32_bf16(vfdt, pf[0], yacc[0][dt], 0,0,0);
      yacc[1][dt] = __builtin_amdgcn_mfma_f32_16x16x32_bf16(vfdt, pf[1], yacc[1][dt], 0,0,0);
    }
  }

  #pragma unroll
  for (int s=0;s<2;s++){
    float ls = lsum[s];
    ls += __shfl_xor(ls, 16);
    ls += __shfl_xor(ls, 32);
    float inv = 1.0f/ls;
    int qrow = qrow0 + s*16 + r16;
    #pragma unroll
    for (int dt=0;dt<4;dt++){
      ushort4 o;
      o.x = (unsigned short)f2bs(yacc[s][dt][0]*inv);
      o.y = (unsigned short)f2bs(yacc[s][dt][1]*inv);
      o.z = (unsigned short)f2bs(yacc[s][dt][2]*inv);
      o.w = (unsigned short)f2bs(yacc[s][dt][3]*inv);
      *reinterpret_cast<ushort4*>(y + baseY + (size_t)qrow*C_ + dt*16 + g*4) = o;
    }
  }
}

// ---------------- final LN (last token only, + W2 bf16 partials) + pooling head ----------------
__global__ __launch_bounds__(256) void head_k(const bf16* __restrict__ hbuf,
    const bf16* __restrict__ p0, const bf16* __restrict__ p1,
    const float* __restrict__ gf, const float* __restrict__ bfv,
    const float* __restrict__ Wp, const float* __restrict__ bp, float* __restrict__ out)
{
  int b = blockIdx.x, kc = blockIdx.y, tid = threadIdx.x;
  int w = tid >> 6, lane = tid & 63;
  size_t base = ((size_t)(b*T_ + T_-1))*C_;
  ushort4 hv = reinterpret_cast<const ushort4*>(hbuf + base)[tid];
  ushort4 a = reinterpret_cast<const ushort4*>(p0 + base)[tid];
  ushort4 c = reinterpret_cast<const ushort4*>(p1 + base)[tid];
  float vx = bs2f(hv.x) + bs2f(a.x) + bs2f(c.x);
  float vy = bs2f(hv.y) + bs2f(a.y) + bs2f(c.y);
  float vz = bs2f(hv.z) + bs2f(a.z) + bs2f(c.z);
  float vw = bs2f(hv.w) + bs2f(a.w) + bs2f(c.w);
  float s = vx+vy+vz+vw;
  float ss = vx*vx+vy*vy+vz*vz+vw*vw;
  #pragma unroll
  for (int o=32;o>=1;o>>=1){ s += __shfl_xor(s,o); ss += __shfl_xor(ss,o); }
  __shared__ float sa[4], sb[4];
  if (lane==0){ sa[w]=s; sb[w]=ss; }
  __syncthreads();
  s  = sa[0]+sa[1]+sa[2]+sa[3];
  ss = sb[0]+sb[1]+sb[2]+sb[3];
  float mean = s * (1.0f/C_);
  float var  = ss * (1.0f/C_) - mean*mean;
  float rs = rsqrtf(var + 1e-5f);
  __shared__ float nrm[C_];
  float4 gv = reinterpret_cast<const float4*>(gf)[tid];
  float4 bv = reinterpret_cast<const float4*>(bfv)[tid];
  nrm[tid*4+0] = (vx-mean)*rs*gv.x + bv.x;
  nrm[tid*4+1] = (vy-mean)*rs*gv.y + bv.y;
  nrm[tid*4+2] = (vz-mean)*rs*gv.z + bv.z;
  nrm[tid*4+3] = (vw-mean)*rs*gv.w + bv.w;
  __syncthreads();
  float acc = (kc==0) ? bp[tid] : 0.f;
  int k0 = kc*64;
  #pragma unroll 8
  for (int kk=k0; kk<k0+64; kk++) acc += nrm[kk]*Wp[(size_t)kk*256 + tid];
  atomicAdd(&out[b*256 + tid], acc);
}

extern "C" void kernel_launch(void* const* d_in, const int* in_sizes, int n_in,
                              void* d_out, int out_size, void* d_ws, size_t ws_size,
                              hipStream_t stream)
{
  const float* x  = (const float*)d_in[0];
  const float* Wq = (const float*)d_in[1];
  const float* bq = (const float*)d_in[2];
  const float* Wk = (const float*)d_in[3];
  const float* bk = (const float*)d_in[4];
  const float* Wv = (const float*)d_in[5];
  const float* bv = (const float*)d_in[6];
  const float* Wo = (const float*)d_in[7];
  const float* bo = (const float*)d_in[8];
  const float* g1 = (const float*)d_in[9];
  const float* be1= (const float*)d_in[10];
  const float* g2 = (const float*)d_in[11];
  const float* be2= (const float*)d_in[12];
  const float* W1 = (const float*)d_in[13];
  const float* b1 = (const float*)d_in[14];
  const float* W2 = (const float*)d_in[15];
  const float* b2 = (const float*)d_in[16];
  const float* gf = (const float*)d_in[17];
  const float* bfv= (const float*)d_in[18];
  const float* Wp = (const float*)d_in[19];
  const float* bp = (const float*)d_in[20];
  float* out = (float*)d_out;

  const size_t NEED = 209715200;
  if (ws_size < NEED) return;

  char* ws = (char*)d_ws;
  bf16* hbuf  = (bf16*)ws;                       //   0 .. 16MiB  bf16 residual
  bf16* abuf  = (bf16*)(ws + 33554432);          //  32 .. 48MiB
  bf16* qkv   = (bf16*)(ws + 50331648);          //  48 .. 96MiB   [M,3C] (aliased by mid)
  bf16* ybuf  = (bf16*)(ws + 100663296);         //  96 ..112MiB   (aliased by mid)
  bf16* mid   = (bf16*)(ws + 50331648);          //  48 ..112MiB   [M,F]
  bf16* slab  = (bf16*)(ws + 117440512);         // 112 ..136MiB   per-layer bf16 Wt
  bf16* part  = (bf16*)(ws + 142606336);         // 136 ..168MiB   2x [M,C] bf16 split-K partials

  cvt_x<<<8192, 256, 0, stream>>>(x, hbuf);
  hipMemsetAsync(d_out, 0, (size_t)out_size*sizeof(float), stream);

  for (int l=0; l<L_; ++l){
    size_t oCC = (size_t)l*C_*C_, oC = (size_t)l*C_;
    size_t oCF = (size_t)l*C_*F_, oF = (size_t)l*F_;
    convert_w<<<12288, 256, 0, stream>>>(Wq+oCC, Wk+oCC, Wv+oCC, Wo+oCC, W1+oCF, W2+oCF, slab);
    // ln1: fold in previous layer's W2 partials (none at l==0)
    ln_k<<<M_, 256, 0, stream>>>(hbuf, part, part + (size_t)M_*C_, l>0 ? 1:0, g1+oC, be1+oC, abuf);
    // fused QKV: [8192,1024] @ [3072,1024]^T -> [8192,3072]
    gemm8_k<0,1><<<dim3(12,32), 512, 0, stream>>>(abuf, C_, slab, C_,
        bq+oC, bk+oC, bv+oC, 1, qkv, 3*C_, C_);
    attn_k<<<dim3(2, H_, B_), 512, 0, stream>>>(qkv, ybuf);
    // Wo: split-K=2 -> bf16 partials
    gemm8_k<2,0><<<dim3(4,32,2), 512, 0, stream>>>(ybuf, C_, slab + (size_t)3*C_*C_, C_,
        bo+oC, bo+oC, bo+oC, 1, part, C_, C_/2);
    // ln2: fold in Wo partials
    ln_k<<<M_, 256, 0, stream>>>(hbuf, part, part + (size_t)M_*C_, 1, g2+oC, be2+oC, abuf);
    // W1: [8192,1024] @ [4096,1024]^T -> GELU -> [8192,4096]
    gemm8_k<1,0><<<dim3(16,32), 512, 0, stream>>>(abuf, C_, slab + (size_t)4*C_*C_, C_,
        b1+oF, b1+oF, b1+oF, 1, mid, F_, C_);
    // W2: split-K=2 -> bf16 partials (folded by next ln1 / head)
    gemm8_k<2,0><<<dim3(4,32,2), 512, 0, stream>>>(mid, F_, slab + (size_t)4*C_*C_ + (size_t)C_*F_, F_,
        b2+oC, b2+oC, b2+oC, 1, part, C_, F_/2);
  }
  head_k<<<dim3(B_,16), 256, 0, stream>>>(hbuf, part, part + (size_t)M_*C_,
      gf, bfv, Wp, bp, out);
}